// Round 4
// baseline (2764.748 us; speedup 1.0000x reference)
//
#include <hip/hip_runtime.h>
#include <hip/hip_cooperative_groups.h>
#include <hip/hip_fp16.h>
#include <math.h>

namespace cg = cooperative_groups;

#define NNODES 100000
#define NEDGES 1600000
#define NGROUP (NEDGES / 4)    // 4-edge groups
#define NLAYERS 20
#define NB 256          // accumulator banks (keeps atomic chains short)
#define BLK 256
#define GRIDE 1024                          // stride kernels (setup)
#define STRIDE (GRIDE * BLK)
#define GRIDL ((NGROUP + BLK - 1) / BLK)    // 1563: one 4-edge group per thread
#define NBLKN ((NNODES + 255) / 256)        // 391 blocks for node kernels
#define GRIDN4 ((NNODES * 4 + BLK - 1) / BLK)  // 4 lanes per node (k3)
#define GRIDC_MAX 768                       // coop grid cap: 3 blocks/CU x 256 CU

struct __align__(8) H4 { __half h[4]; };    // 4 halfs, 8B load/store

// ---- block reduce of N float stats -> N parallel f64 atomics (one per lane) ----
template<int N>
__device__ __forceinline__ void block_stats_atomic(const float* vals, double* base) {
  __shared__ float sm[8][4];
  int lane = threadIdx.x & 63, wid = threadIdx.x >> 6;
  __syncthreads();                  // guard back-to-back calls reusing sm
  #pragma unroll
  for (int n = 0; n < N; ++n) {
    float d = vals[n];
    #pragma unroll
    for (int o = 32; o > 0; o >>= 1) d += __shfl_down(d, o, 64);
    if (lane == 0) sm[n][wid] = d;
  }
  __syncthreads();
  if (threadIdx.x < N) {
    double s = (double)sm[threadIdx.x][0] + (double)sm[threadIdx.x][1]
             + (double)sm[threadIdx.x][2] + (double)sm[threadIdx.x][3];
    atomicAdd(base + threadIdx.x, s);
  }
}

// ---- reduce NB banks via per-wave shuffle butterfly ----
template<int NS>
__device__ __forceinline__ void bank_reduce(const double* __restrict__ acc, double* res) {
  __shared__ double part[4][8];
  __syncthreads();                  // guard reuse across repeated calls
  int t = threadIdx.x;              // 256 threads = 4 waves x 64 = NB banks
  double v[NS];
  #pragma unroll
  for (int s = 0; s < NS; ++s) v[s] = acc[t * 8 + s];
  #pragma unroll
  for (int o = 32; o > 0; o >>= 1)
    #pragma unroll
    for (int s = 0; s < NS; ++s) v[s] += __shfl_down(v[s], o, 64);
  if ((t & 63) == 0) {
    int w = t >> 6;
    #pragma unroll
    for (int s = 0; s < NS; ++s) part[w][s] = v[s];
  }
  __syncthreads();
  #pragma unroll
  for (int s = 0; s < NS; ++s) res[s] = part[0][s] + part[1][s] + part[2][s] + part[3][s];
}

// x = [mi, mj, h] @ W1 + b1  (9->4)
__device__ __forceinline__ void compute_x(const float4 mi, const float4 mj,
    float h0, float h1, float h2,
    const float* __restrict__ w, const float* __restrict__ b, float* x) {
  #pragma unroll
  for (int j = 0; j < 4; ++j) {
    float t = b[j];
    t += mi.x * w[0 * 4 + j]; t += mi.y * w[1 * 4 + j]; t += mi.z * w[2 * 4 + j];
    t += mj.x * w[3 * 4 + j]; t += mj.y * w[4 * 4 + j]; t += mj.z * w[5 * 4 + j];
    t += h0 * w[6 * 4 + j];  t += h1 * w[7 * 4 + j];  t += h2 * w[8 * 4 + j];
    x[j] = t;
  }
}

// ---------------- kz: pad-copy M, zero hist + accums ----------------
__global__ void __launch_bounds__(BLK) kz(const float* __restrict__ Min,
                                          float* __restrict__ M,
                                          int* __restrict__ hist,
                                          double* __restrict__ accs) {
  int tid = blockIdx.x * BLK + threadIdx.x;
  for (int v = tid; v < NNODES; v += STRIDE) {
    float4 m;
    m.x = Min[3 * v]; m.y = Min[3 * v + 1]; m.z = Min[3 * v + 2]; m.w = 0.f;
    *(float4*)(M + 4 * (size_t)v) = m;
    hist[v] = 0;
  }
  for (int i = tid; i < 3 * NB * 8; i += STRIDE) accs[i] = 0.0;
}

// ---------------- khr: histogram of dst, save rank (atomic return) ----------
__global__ void __launch_bounds__(BLK) khr(const int* __restrict__ dst,
                                           int* __restrict__ hist,
                                           int* __restrict__ rankpos) {
  int g = blockIdx.x * BLK + threadIdx.x;
  if (g >= NGROUP) return;
  int4 d4 = ((const int4*)dst)[g];
  int4 r;
  r.x = atomicAdd(&hist[d4.x], 1);
  r.y = atomicAdd(&hist[d4.y], 1);
  r.z = atomicAdd(&hist[d4.z], 1);
  r.w = atomicAdd(&hist[d4.w], 1);
  ((int4*)rankpos)[g] = r;
}

// ---------------- ksA: per-block sums of hist ----------------
__global__ void __launch_bounds__(256) ksA(const int* __restrict__ hist,
                                           int* __restrict__ bsum) {
  __shared__ int sm[256];
  int i = blockIdx.x * 256 + threadIdx.x;
  sm[threadIdx.x] = (i < NNODES) ? hist[i] : 0;
  __syncthreads();
  for (int o = 128; o > 0; o >>= 1) {
    if (threadIdx.x < o) sm[threadIdx.x] += sm[threadIdx.x + o];
    __syncthreads();
  }
  if (threadIdx.x == 0) bsum[blockIdx.x] = sm[0];
}

// ---------------- ksB: exclusive scan of the 391 block sums (1 block) -------
__global__ void __launch_bounds__(512) ksB(const int* __restrict__ bsum,
                                           int* __restrict__ bbase) {
  __shared__ int sm[512];
  int t = threadIdx.x;
  sm[t] = (t < NBLKN) ? bsum[t] : 0;
  __syncthreads();
  for (int o = 1; o < 512; o <<= 1) {
    int v = (t >= o) ? sm[t - o] : 0;
    __syncthreads();
    sm[t] += v;
    __syncthreads();
  }
  if (t < NBLKN) bbase[t] = (t == 0) ? 0 : sm[t - 1];
}

// ---------------- ksC: per-element offsets + dp fill ----------------
__global__ void __launch_bounds__(256) ksC(const int* __restrict__ hist,
                                           const int* __restrict__ bbase,
                                           int* __restrict__ off,
                                           int* __restrict__ dp) {
  __shared__ int sm[256];
  int t = threadIdx.x;
  int i = blockIdx.x * 256 + t;
  int v = (i < NNODES) ? hist[i] : 0;
  sm[t] = v;
  __syncthreads();
  for (int o = 1; o < 256; o <<= 1) {
    int u = (t >= o) ? sm[t - o] : 0;
    __syncthreads();
    sm[t] += u;
    __syncthreads();
  }
  if (i < NNODES) {
    int ex = bbase[blockIdx.x] + sm[t] - v;
    off[i] = ex;
    for (int e = ex; e < ex + v; ++e) dp[e] = i;   // CSR-order dst fill
  }
  if (i == 0) off[NNODES] = NEDGES;
}

// ---------------- kpk: pack dp groups as {base, 3x u8 deltas} ----------------
__global__ void __launch_bounds__(BLK) kpk(const int* __restrict__ dp,
                                           int2* __restrict__ dpp) {
  int g = blockIdx.x * BLK + threadIdx.x;
  if (g >= NGROUP) return;
  int4 d4 = ((const int4*)dp)[g];
  int2 o;
  o.x = d4.x;
  o.y = (d4.y - d4.x) | ((d4.z - d4.x) << 8) | ((d4.w - d4.x) << 16);
  dpp[g] = o;
}

// ---------------- kp1: pos[e] = off[dst]+rank (in-place), eperm scatter -----
__global__ void __launch_bounds__(BLK) kp1(const int* __restrict__ dst,
                                           const int* __restrict__ off,
                                           int* __restrict__ rankpos,
                                           int* __restrict__ eperm) {
  int g = blockIdx.x * BLK + threadIdx.x;
  if (g >= NGROUP) return;
  int4 d4 = ((const int4*)dst)[g];
  int4 r4 = ((int4*)rankpos)[g];
  int4 p4;
  p4.x = off[d4.x] + r4.x;
  p4.y = off[d4.y] + r4.y;
  p4.z = off[d4.z] + r4.z;
  p4.w = off[d4.w] + r4.w;
  int e = 4 * g;
  eperm[p4.x] = e; eperm[p4.y] = e + 1; eperm[p4.z] = e + 2; eperm[p4.w] = e + 3;
  ((int4*)rankpos)[g] = p4;   // rankpos now holds pos[e]
}

// ---------------- kp2: gather src/H into CSR order (H -> fp16) --------------
__global__ void __launch_bounds__(BLK) kp2(const int* __restrict__ src,
                                           const float* __restrict__ Hin,
                                           const int* __restrict__ eperm,
                                           int* __restrict__ sp,
                                           __half* __restrict__ Hp) {
  int g = blockIdx.x * BLK + threadIdx.x;
  if (g >= NGROUP) return;
  int4 e4 = ((const int4*)eperm)[g];
  int4 s4;
  s4.x = src[e4.x];
  s4.y = src[e4.y];
  s4.z = src[e4.z];
  s4.w = src[e4.w];
  __half hh[12];
  int ee[4] = {e4.x, e4.y, e4.z, e4.w};
  #pragma unroll
  for (int k = 0; k < 4; ++k) {
    size_t e3 = 3 * (size_t)ee[k];
    hh[3 * k]     = __float2half(Hin[e3]);
    hh[3 * k + 1] = __float2half(Hin[e3 + 1]);
    hh[3 * k + 2] = __float2half(Hin[e3 + 2]);
  }
  ((int4*)sp)[g] = s4;
  H4* Hv = (H4*)(Hp + 12 * (size_t)g);
  H4 a, b, c;
  #pragma unroll
  for (int i = 0; i < 4; ++i) { a.h[i] = hh[i]; b.h[i] = hh[4 + i]; c.h[i] = hh[8 + i]; }
  Hv[0] = a; Hv[1] = b; Hv[2] = c;
}

// ======================= shared phase bodies (device) =======================
__device__ __forceinline__ void phaseA_body(int g,
    const float* __restrict__ M, const __half* __restrict__ Hp,
    __half* __restrict__ xb, const int* __restrict__ sp,
    const int2* __restrict__ dpp, const float* __restrict__ W1,
    const float* __restrict__ b1, float* sx, float* sq) {
  int4 s4 = ((const int4*)sp)[g];
  int2 dg = dpp[g];
  int d0 = dg.x;
  int d1 = d0 + (dg.y & 255);
  int d2 = d0 + ((dg.y >> 8) & 255);
  int d3 = d0 + ((dg.y >> 16) & 255);
  const H4* Hv = (const H4*)(Hp + 12 * (size_t)g);
  H4 a = Hv[0], b = Hv[1], c = Hv[2];
  float hf[12];
  #pragma unroll
  for (int i = 0; i < 4; ++i) {
    hf[i] = __half2float(a.h[i]); hf[4 + i] = __half2float(b.h[i]); hf[8 + i] = __half2float(c.h[i]);
  }
  float4 mi0 = *(const float4*)(M + 4 * (size_t)d0);
  float4 mj0 = *(const float4*)(M + 4 * (size_t)s4.x);
  float4 mi1 = *(const float4*)(M + 4 * (size_t)d1);
  float4 mj1 = *(const float4*)(M + 4 * (size_t)s4.y);
  float4 mi2 = *(const float4*)(M + 4 * (size_t)d2);
  float4 mj2 = *(const float4*)(M + 4 * (size_t)s4.z);
  float4 mi3 = *(const float4*)(M + 4 * (size_t)d3);
  float4 mj3 = *(const float4*)(M + 4 * (size_t)s4.w);
  float x[4][4];
  compute_x(mi0, mj0, hf[0], hf[1], hf[2],  W1, b1, x[0]);
  compute_x(mi1, mj1, hf[3], hf[4], hf[5],  W1, b1, x[1]);
  compute_x(mi2, mj2, hf[6], hf[7], hf[8],  W1, b1, x[2]);
  compute_x(mi3, mj3, hf[9], hf[10], hf[11], W1, b1, x[3]);
  H4* xv = (H4*)xb + 4 * (size_t)g;
  #pragma unroll
  for (int k = 0; k < 4; ++k) {
    H4 xo;
    #pragma unroll
    for (int j = 0; j < 4; ++j) {
      __half hx = __float2half(x[k][j]);
      xo.h[j] = hx;
      float v = __half2float(hx);       // stats on the ROUNDED values
      sx[j] += v; sq[j] += v * v;
    }
    xv[k] = xo;
  }
}

__device__ __forceinline__ void phaseB_body(int g, int isFinal,
    const float* __restrict__ M, __half* __restrict__ Hp,
    const __half* __restrict__ xb, const int2* __restrict__ dpp,
    const float* s1, const float* t1,
    const float* __restrict__ W2, const float* __restrict__ b2,
    const float* __restrict__ V1, const float* __restrict__ vb1,
    const float* __restrict__ OW1, const float* __restrict__ ob1,
    float* sz, float* szz, float* sf, float* sff) {
  int2 dg = dpp[g];
  int dd[4];
  dd[0] = dg.x;
  dd[1] = dd[0] + (dg.y & 255);
  dd[2] = dd[0] + ((dg.y >> 8) & 255);
  dd[3] = dd[0] + ((dg.y >> 16) & 255);
  float4 mi[4];
  mi[0] = *(const float4*)(M + 4 * (size_t)dd[0]);
  mi[1] = *(const float4*)(M + 4 * (size_t)dd[1]);
  mi[2] = *(const float4*)(M + 4 * (size_t)dd[2]);
  mi[3] = *(const float4*)(M + 4 * (size_t)dd[3]);
  const H4* xv = (const H4*)xb + 4 * (size_t)g;
  __half hh[12];
  #pragma unroll
  for (int k = 0; k < 4; ++k) {
    H4 xh = xv[k];
    float y[4];
    #pragma unroll
    for (int j = 0; j < 4; ++j)
      y[j] = fmaxf(__half2float(xh.h[j]) * s1[j] + t1[j], 0.f);
    float hr[3];
    #pragma unroll
    for (int c = 0; c < 3; ++c) {
      float v = b2[c] + y[0] * W2[0 * 3 + c] + y[1] * W2[1 * 3 + c]
                      + y[2] * W2[2 * 3 + c] + y[3] * W2[3 * 3 + c];
      __half hv = __float2half(v);
      hh[3 * k + c] = hv;
      hr[c] = __half2float(hv);     // rounded value: what A/C will read back
    }
    #pragma unroll
    for (int c = 0; c < 3; ++c) {
      float z = vb1[c] + mi[k].x * V1[0 * 3 + c] + mi[k].y * V1[1 * 3 + c] + mi[k].z * V1[2 * 3 + c]
                       + hr[0] * V1[3 * 3 + c] + hr[1] * V1[4 * 3 + c] + hr[2] * V1[5 * 3 + c];
      sz[c] += z; szz[c] += z * z;
    }
    if (isFinal) {
      #pragma unroll
      for (int c = 0; c < 3; ++c) {
        float f = ob1[c] + hr[0] * OW1[0 * 3 + c] + hr[1] * OW1[1 * 3 + c] + hr[2] * OW1[2 * 3 + c];
        sf[c] += f; sff[c] += f * f;
      }
    }
  }
  H4* Hw = (H4*)(Hp + 12 * (size_t)g);
  H4 oA, oB, oC;
  #pragma unroll
  for (int i = 0; i < 4; ++i) { oA.h[i] = hh[i]; oB.h[i] = hh[4 + i]; oC.h[i] = hh[8 + i]; }
  Hw[0] = oA; Hw[1] = oB; Hw[2] = oC;
}

__device__ __forceinline__ void phaseC_body(int idx,
    float* __restrict__ M, const __half* __restrict__ Hp,
    const int* __restrict__ off,
    const float* s2, const float* t2,
    const float* __restrict__ V1, const float* __restrict__ vb1,
    const float* __restrict__ V2, const float* __restrict__ vb2) {
  int v = idx >> 2, q = idx & 3;
  float4 mi = *(const float4*)(M + 4 * (size_t)v);
  int e0 = off[v], e1 = off[v + 1];
  float a0 = 0.f, a1 = 0.f, a2v = 0.f;
  for (int e = e0 + q; e < e1; e += 4) {
    size_t e3 = 3 * (size_t)e;
    float h0 = __half2float(Hp[e3]), h1 = __half2float(Hp[e3 + 1]), h2 = __half2float(Hp[e3 + 2]);
    float y[3];
    #pragma unroll
    for (int c = 0; c < 3; ++c) {
      float z = vb1[c] + mi.x * V1[0 * 3 + c] + mi.y * V1[1 * 3 + c] + mi.z * V1[2 * 3 + c]
                       + h0 * V1[3 * 3 + c] + h1 * V1[4 * 3 + c] + h2 * V1[5 * 3 + c];
      y[c] = fmaxf(z * s2[c] + t2[c], 0.f);
    }
    a0  += vb2[0] + y[0] * V2[0] + y[1] * V2[3] + y[2] * V2[6];
    a1  += vb2[1] + y[0] * V2[1] + y[1] * V2[4] + y[2] * V2[7];
    a2v += vb2[2] + y[0] * V2[2] + y[1] * V2[5] + y[2] * V2[8];
  }
  a0  += __shfl_down(a0, 2, 4);  a0  += __shfl_down(a0, 1, 4);
  a1  += __shfl_down(a1, 2, 4);  a1  += __shfl_down(a1, 1, 4);
  a2v += __shfl_down(a2v, 2, 4); a2v += __shfl_down(a2v, 1, 4);
  if (q == 0) {
    float4 o; o.x = a0; o.y = a1; o.z = a2v; o.w = 0.f;
    *(float4*)(M + 4 * (size_t)v) = o;   // in place: only lanes of v read M[v]
  }
}

__device__ __forceinline__ void phaseF_body(int g,
    const __half* __restrict__ Hp, const int* __restrict__ pos,
    const float* sF, const float* tF,
    const float* __restrict__ OW1, const float* __restrict__ ob1,
    const float* __restrict__ OW2, const float* __restrict__ ob2,
    float* __restrict__ outp) {
  int4 p4 = ((const int4*)pos)[g];
  int p[4] = {p4.x, p4.y, p4.z, p4.w};
  float2 o[4];
  #pragma unroll
  for (int k = 0; k < 4; ++k) {
    size_t p3 = 3 * (size_t)p[k];
    float h0 = __half2float(Hp[p3]), h1 = __half2float(Hp[p3 + 1]), h2 = __half2float(Hp[p3 + 2]);
    float y[3];
    #pragma unroll
    for (int c = 0; c < 3; ++c) {
      float f = ob1[c] + h0 * OW1[0 * 3 + c] + h1 * OW1[1 * 3 + c] + h2 * OW1[2 * 3 + c];
      y[c] = fmaxf(f * sF[c] + tF[c], 0.f);
    }
    float l0 = ob2[0] + y[0] * OW2[0] + y[1] * OW2[2] + y[2] * OW2[4];
    float l1 = ob2[1] + y[0] * OW2[1] + y[1] * OW2[3] + y[2] * OW2[5];
    float mx = fmaxf(l0, l1);
    float e0 = __expf(l0 - mx), e1 = __expf(l1 - mx);
    float inv = 1.f / (e0 + e1);
    o[k].x = e0 * inv; o[k].y = e1 * inv;
  }
  float4 oA, oB;
  oA.x = o[0].x; oA.y = o[0].y; oA.z = o[1].x; oA.w = o[1].y;
  oB.x = o[2].x; oB.y = o[2].y; oB.z = o[3].x; oB.w = o[3].y;
  ((float4*)outp)[2 * (size_t)g] = oA;
  ((float4*)outp)[2 * (size_t)g + 1] = oB;
}

__device__ __forceinline__ void bn_coeff(const double* red, int n,
    const float* g, const float* be, float* s, float* t) {
  const double invE = 1.0 / (double)NEDGES;
  for (int c = 0; c < n; ++c) {
    double m = red[c] * invE;
    double var = red[n + c] * invE - m * m;
    double sc = (double)g[c] / sqrt(var + 1e-5);
    s[c] = (float)sc;
    t[c] = (float)((double)be[c] - m * sc);
  }
}

// ============ kloop: fused 20-layer loop + head (cooperative) ============
// Grid-stride phases; works for any grid size. All producer->consumer edges
// cross a grid.sync(). acc rotation: A zeroes acc2, C zeroes acc1.
__global__ void __launch_bounds__(BLK, 3) kloop(
    float* __restrict__ M, __half* __restrict__ Hp, __half* __restrict__ xb,
    const int* __restrict__ sp, const int2* __restrict__ dpp,
    const int* __restrict__ off, const int* __restrict__ pos,
    const float* __restrict__ W1, const float* __restrict__ b1,
    const float* __restrict__ g1, const float* __restrict__ be1,
    const float* __restrict__ W2, const float* __restrict__ b2,
    const float* __restrict__ V1, const float* __restrict__ vb1,
    const float* __restrict__ vg1, const float* __restrict__ vbe1,
    const float* __restrict__ V2, const float* __restrict__ vb2,
    const float* __restrict__ OW1, const float* __restrict__ ob1,
    const float* __restrict__ og, const float* __restrict__ obe,
    const float* __restrict__ OW2, const float* __restrict__ ob2,
    double* __restrict__ acc1, double* __restrict__ acc2,
    double* __restrict__ accF, float* __restrict__ outp) {
  cg::grid_group grid = cg::this_grid();
  const int tid = blockIdx.x * BLK + threadIdx.x;
  const int gsize = gridDim.x * BLK;
  const size_t bank = (size_t)(blockIdx.x & (NB - 1)) * 8;

  for (int l = 0; l < NLAYERS; ++l) {
    const int isFinal = (l == NLAYERS - 1);

    // -------- Phase A: x = e_in @ W1 + b1 -> xb ; stats of x --------
    if (blockIdx.x == 0)
      for (int i = threadIdx.x; i < NB * 8; i += BLK) acc2[i] = 0.0;
    float sx[4] = {0, 0, 0, 0}, sq[4] = {0, 0, 0, 0};
    for (int g = tid; g < NGROUP; g += gsize)
      phaseA_body(g, M, Hp, xb, sp, dpp, W1, b1, sx, sq);
    {
      float va[8] = {sx[0], sx[1], sx[2], sx[3], sq[0], sq[1], sq[2], sq[3]};
      block_stats_atomic<8>(va, acc1 + bank);
    }
    grid.sync();

    // -------- Phase B: Hn per edge (in place) + stats of z --------
    double red[8];
    bank_reduce<8>(acc1, red);
    float s1[4], t1[4];
    bn_coeff(red, 4, g1, be1, s1, t1);
    float sz[3] = {0, 0, 0}, szz[3] = {0, 0, 0}, sf[3] = {0, 0, 0}, sff[3] = {0, 0, 0};
    for (int g = tid; g < NGROUP; g += gsize)
      phaseB_body(g, isFinal, M, Hp, xb, dpp, s1, t1, W2, b2, V1, vb1, OW1, ob1,
                  sz, szz, sf, sff);
    {
      float v6[6] = {sz[0], sz[1], sz[2], szz[0], szz[1], szz[2]};
      block_stats_atomic<6>(v6, acc2 + bank);
    }
    if (isFinal) {
      float v6b[6] = {sf[0], sf[1], sf[2], sff[0], sff[1], sff[2]};
      block_stats_atomic<6>(v6b, accF + bank);
      break;
    }
    grid.sync();

    // -------- Phase C: node aggregation (4 lanes/node), M in place --------
    double r2[6];
    bank_reduce<6>(acc2, r2);
    float s2[3], t2[3];
    bn_coeff(r2, 3, vg1, vbe1, s2, t2);
    if (blockIdx.x == 0)
      for (int i = threadIdx.x; i < NB * 8; i += BLK) acc1[i] = 0.0;
    for (int idx = tid; idx < NNODES * 4; idx += gsize)
      phaseC_body(idx, M, Hp, off, s2, t2, V1, vb1, V2, vb2);
    grid.sync();
  }

  grid.sync();   // final-layer Hp + accF complete

  // -------- Phase F: head --------
  double rF[6];
  bank_reduce<6>(accF, rF);
  float sF[3], tF[3];
  bn_coeff(rF, 3, og, obe, sF, tF);
  for (int g = tid; g < NGROUP; g += gsize)
    phaseF_body(g, Hp, pos, sF, tF, OW1, ob1, OW2, ob2, outp);
}

// ======================= split-path kernels (fallback) =======================
__global__ void __launch_bounds__(BLK) k1(
    const float* __restrict__ M, const __half* __restrict__ H,
    __half* __restrict__ xb,
    const int* __restrict__ sp, const int2* __restrict__ dpp,
    const float* __restrict__ W1, const float* __restrict__ b1,
    double* __restrict__ acc1, double* __restrict__ acc2) {
  int g = blockIdx.x * BLK + threadIdx.x;
  if (blockIdx.x == 0)
    for (int i = threadIdx.x; i < NB * 8; i += BLK) acc2[i] = 0.0;
  float sx[4] = {0, 0, 0, 0}, sq[4] = {0, 0, 0, 0};
  if (g < NGROUP)
    phaseA_body(g, M, H, xb, sp, dpp, W1, b1, sx, sq);
  float vals[8] = {sx[0], sx[1], sx[2], sx[3], sq[0], sq[1], sq[2], sq[3]};
  block_stats_atomic<8>(vals, acc1 + (size_t)(blockIdx.x & (NB - 1)) * 8);
}

__global__ void __launch_bounds__(BLK) k2(
    const float* __restrict__ M, __half* __restrict__ Hn,
    const __half* __restrict__ xb, const int2* __restrict__ dpp,
    const float* __restrict__ g1, const float* __restrict__ be1,
    const float* __restrict__ W2, const float* __restrict__ b2,
    const float* __restrict__ V1, const float* __restrict__ vb1,
    const double* __restrict__ acc1, double* __restrict__ acc2,
    int isFinal,
    const float* __restrict__ OW1, const float* __restrict__ ob1,
    double* __restrict__ accF) {
  double red[8];
  bank_reduce<8>(acc1, red);
  float s1[4], t1[4];
  bn_coeff(red, 4, g1, be1, s1, t1);
  float sz[3] = {0, 0, 0}, szz[3] = {0, 0, 0}, sf[3] = {0, 0, 0}, sff[3] = {0, 0, 0};
  int g = blockIdx.x * BLK + threadIdx.x;
  if (g < NGROUP)
    phaseB_body(g, isFinal, M, Hn, xb, dpp, s1, t1, W2, b2, V1, vb1, OW1, ob1,
                sz, szz, sf, sff);
  size_t bank = (size_t)(blockIdx.x & (NB - 1)) * 8;
  float v6[6] = {sz[0], sz[1], sz[2], szz[0], szz[1], szz[2]};
  block_stats_atomic<6>(v6, acc2 + bank);
  if (isFinal) {
    float v6b[6] = {sf[0], sf[1], sf[2], sff[0], sff[1], sff[2]};
    block_stats_atomic<6>(v6b, accF + bank);
  }
}

__global__ void __launch_bounds__(BLK) k3(
    float* __restrict__ M, const __half* __restrict__ Hn,
    const int* __restrict__ off,
    const float* __restrict__ V1, const float* __restrict__ vb1,
    const float* __restrict__ vg1, const float* __restrict__ vbe1,
    const float* __restrict__ V2, const float* __restrict__ vb2,
    const double* __restrict__ acc2, double* __restrict__ acc1) {
  double red[6];
  bank_reduce<6>(acc2, red);
  float s2[3], t2[3];
  bn_coeff(red, 3, vg1, vbe1, s2, t2);
  if (blockIdx.x == 0)
    for (int i = threadIdx.x; i < NB * 8; i += BLK) acc1[i] = 0.0;
  int idx = blockIdx.x * BLK + threadIdx.x;
  if ((idx >> 2) >= NNODES) return;
  phaseC_body(idx, M, Hn, off, s2, t2, V1, vb1, V2, vb2);
}

__global__ void __launch_bounds__(BLK) f2(
    const __half* __restrict__ H, const int* __restrict__ pos,
    const float* __restrict__ OW1, const float* __restrict__ ob1,
    const float* __restrict__ og, const float* __restrict__ obe,
    const float* __restrict__ OW2, const float* __restrict__ ob2,
    const double* __restrict__ accF, float* __restrict__ out) {
  double red[6];
  bank_reduce<6>(accF, red);
  float sF[3], tF[3];
  bn_coeff(red, 3, og, obe, sF, tF);
  int g = blockIdx.x * BLK + threadIdx.x;
  if (g >= NGROUP) return;
  phaseF_body(g, H, pos, sF, tF, OW1, ob1, OW2, ob2, out);
}

extern "C" void kernel_launch(void* const* d_in, const int* in_sizes, int n_in,
                              void* d_out, int out_size, void* d_ws, size_t ws_size,
                              hipStream_t stream) {
  const float* M_in   = (const float*)d_in[0];
  const float* H_in   = (const float*)d_in[1];
  const int*   ei     = (const int*)d_in[2];
  const float* we_w1  = (const float*)d_in[3];
  const float* we_b1  = (const float*)d_in[4];
  const float* we_g1  = (const float*)d_in[5];
  const float* we_be1 = (const float*)d_in[6];
  const float* we_w2  = (const float*)d_in[7];
  const float* we_b2  = (const float*)d_in[8];
  const float* wv_w1  = (const float*)d_in[9];
  const float* wv_b1  = (const float*)d_in[10];
  const float* wv_g1  = (const float*)d_in[11];
  const float* wv_be1 = (const float*)d_in[12];
  const float* wv_w2  = (const float*)d_in[13];
  const float* wv_b2  = (const float*)d_in[14];
  const float* out_w1 = (const float*)d_in[15];
  const float* out_b1 = (const float*)d_in[16];
  const float* out_g  = (const float*)d_in[17];
  const float* out_be = (const float*)d_in[18];
  const float* out_w2 = (const float*)d_in[19];
  const float* out_b2 = (const float*)d_in[20];
  const int* src = ei;
  const int* dst = ei + NEDGES;

  float* ws = (float*)d_ws;
  float* M     = ws;                         // N*4 floats (in-place across layers)
  __half* Hp   = (__half*)(ws + 400000);     // E*3 halfs (in-place across layers)
  __half* xb   = (__half*)(ws + 2800000);    // E*4 halfs staged x
  int* ib      = (int*)(ws + 6000000);       // int region
  int* sp      = ib;                         // E
  int* dp      = ib + 1600000;               // E (setup only; aliased as eperm)
  int* rankpos = ib + 3200000;               // E (rank, then pos; head reads)
  int2* dpp    = (int2*)(ib + 4800000);      // E/4 int2 = E/2 ints
  int* hist    = ib + 5600000;               // N
  int* off     = ib + 5700000;               // N+1
  int* bsum    = ib + 5800001;               // 400
  int* bbase   = ib + 5800401;               // 400 -> region end 5800801
  double* accs = (double*)(ws + 6000000 + 5800802);  // even float idx -> 8B-aligned
  double* acc1 = accs;
  double* acc2 = accs + NB * 8;
  double* accF = accs + 2 * NB * 8;
  int* eperm   = dp;   // alias: dp dead after kpk, eperm born in kp1
  float* outp  = (float*)d_out;

  // --- build CSR permutation (ws is re-poisoned between replays) ---
  kz<<<GRIDE, BLK, 0, stream>>>(M_in, M, hist, accs);
  khr<<<GRIDL, BLK, 0, stream>>>(dst, hist, rankpos);
  ksA<<<NBLKN, 256, 0, stream>>>(hist, bsum);
  ksB<<<1, 512, 0, stream>>>(bsum, bbase);
  ksC<<<NBLKN, 256, 0, stream>>>(hist, bbase, off, dp);
  kpk<<<GRIDL, BLK, 0, stream>>>(dp, dpp);
  kp1<<<GRIDL, BLK, 0, stream>>>(dst, off, rankpos, eperm);
  kp2<<<GRIDL, BLK, 0, stream>>>(src, H_in, eperm, sp, Hp);

  // --- coop-grid sizing (once per process) ---
  static int g_coop = -1;   // -1 unknown, 0 broken, 1 works
  static int g_grid = 0;
  if (g_grid == 0) {
    int dev = 0;
    (void)hipGetDevice(&dev);
    int nCU = 0;
    if (hipDeviceGetAttribute(&nCU, hipDeviceAttributeMultiprocessorCount, dev)
          != hipSuccess || nCU <= 0) nCU = 256;
    int perCU = 0;
    if (hipOccupancyMaxActiveBlocksPerMultiprocessor(&perCU, kloop, BLK, 0)
          != hipSuccess || perCU <= 0) perCU = 1;
    long cap = (long)perCU * nCU;
    g_grid = (int)(cap < GRIDC_MAX ? cap : GRIDC_MAX);
    if (g_grid < 64) g_grid = 64;    // still correct (grid-stride), just slower
  }

  hipStreamCaptureStatus cst = hipStreamCaptureStatusNone;
  (void)hipStreamIsCapturing(stream, &cst);
  const bool capturing = (cst != hipStreamCaptureStatusNone);
  bool try_coop = (g_coop == 1) || (g_coop == -1 && !capturing);

  bool coop_done = false;
  if (try_coop) {
    void* kargs[] = {
      (void*)&M, (void*)&Hp, (void*)&xb, (void*)&sp, (void*)&dpp, (void*)&off, (void*)&rankpos,
      (void*)&we_w1, (void*)&we_b1, (void*)&we_g1, (void*)&we_be1, (void*)&we_w2, (void*)&we_b2,
      (void*)&wv_w1, (void*)&wv_b1, (void*)&wv_g1, (void*)&wv_be1, (void*)&wv_w2, (void*)&wv_b2,
      (void*)&out_w1, (void*)&out_b1, (void*)&out_g, (void*)&out_be, (void*)&out_w2, (void*)&out_b2,
      (void*)&acc1, (void*)&acc2, (void*)&accF, (void*)&outp
    };
    hipError_t e = hipLaunchCooperativeKernel((void*)kloop, dim3(g_grid), dim3(BLK),
                                              kargs, 0, stream);
    if (e == hipSuccess) {
      coop_done = true;
      if (g_coop == -1) g_coop = 1;
    } else {
      g_coop = 0;
      (void)hipGetLastError();   // clear sticky error
    }
  }

  if (!coop_done) {
    // proven split path (round-1 structure, 1150 us)
    for (int l = 0; l < NLAYERS; ++l) {
      k1<<<GRIDL, BLK, 0, stream>>>(M, Hp, xb, sp, dpp, we_w1, we_b1, acc1, acc2);
      k2<<<GRIDL, BLK, 0, stream>>>(M, Hp, xb, dpp, we_g1, we_be1,
                                    we_w2, we_b2, wv_w1, wv_b1, acc1, acc2,
                                    (l == NLAYERS - 1) ? 1 : 0, out_w1, out_b1, accF);
      if (l < NLAYERS - 1)
        k3<<<GRIDN4, BLK, 0, stream>>>(
            M, Hp, off, wv_w1, wv_b1, wv_g1, wv_be1, wv_w2, wv_b2, acc2, acc1);
    }
    f2<<<GRIDL, BLK, 0, stream>>>(Hp, rankpos, out_w1, out_b1, out_g, out_be,
                                  out_w2, out_b2, accF, outp);
  }
}

// Round 5
// 1239.431 us; speedup vs baseline: 2.2307x; 2.2307x over previous
//
#include <hip/hip_runtime.h>
#include <hip/hip_fp16.h>
#include <math.h>

#define NNODES 100000
#define NEDGES 1600000
#define NGROUP (NEDGES / 4)    // 4-edge groups
#define NLAYERS 20
#define NB 256          // accumulator banks == BLK (keeps atomic chains ~6 deep)
#define BLK 256
#define GRIDE 1024                          // stride kernels (setup)
#define STRIDE (GRIDE * BLK)
#define GRIDL ((NGROUP + BLK - 1) / BLK)    // 1563: one 4-edge group per thread
#define GRIDL2 ((NGROUP / 2 + BLK - 1) / BLK)  // 782: two groups per thread (k1)
#define NBLKN ((NNODES + 255) / 256)        // 391 blocks for node kernels
#define GRIDN4 ((NNODES * 4 + BLK - 1) / BLK)  // 4 lanes per node (k3)

struct __align__(8) H4 { __half h[4]; };    // 4 halfs, 8B load/store
// Hp layout: ONE H4 PER EDGE (h[3] = pad). 8B aligned vector load per edge
// everywhere (k3/f2 were doing 3 scalar fp16 loads per edge before).

// ---- block reduce of N float stats -> N parallel f64 atomics (one per lane) ----
// f32 wave butterflies; f64 from the 4 wave partials upward.
template<int N>
__device__ __forceinline__ void block_stats_atomic(const float* vals, double* base) {
  __shared__ float sm[8][4];
  int lane = threadIdx.x & 63, wid = threadIdx.x >> 6;
  __syncthreads();                  // guard back-to-back calls reusing sm
  #pragma unroll
  for (int n = 0; n < N; ++n) {
    float d = vals[n];
    #pragma unroll
    for (int o = 32; o > 0; o >>= 1) d += __shfl_down(d, o, 64);
    if (lane == 0) sm[n][wid] = d;
  }
  __syncthreads();
  if (threadIdx.x < N) {
    double s = (double)sm[threadIdx.x][0] + (double)sm[threadIdx.x][1]
             + (double)sm[threadIdx.x][2] + (double)sm[threadIdx.x][3];
    atomicAdd(base + threadIdx.x, s);
  }
}

// ---- prologue: reduce NB banks via per-wave shuffle butterfly ----
template<int NS>
__device__ __forceinline__ void bank_reduce(const double* __restrict__ acc, double* res) {
  __shared__ double part[4][8];
  int t = threadIdx.x;               // 256 threads = 4 waves x 64 = NB banks
  double v[NS];
  #pragma unroll
  for (int s = 0; s < NS; ++s) v[s] = acc[t * 8 + s];
  #pragma unroll
  for (int o = 32; o > 0; o >>= 1)
    #pragma unroll
    for (int s = 0; s < NS; ++s) v[s] += __shfl_down(v[s], o, 64);
  if ((t & 63) == 0) {
    int w = t >> 6;
    #pragma unroll
    for (int s = 0; s < NS; ++s) part[w][s] = v[s];
  }
  __syncthreads();
  #pragma unroll
  for (int s = 0; s < NS; ++s) res[s] = part[0][s] + part[1][s] + part[2][s] + part[3][s];
}

// x = [mi, mj, h] @ W1 + b1  (9->4)
__device__ __forceinline__ void compute_x(const float4 mi, const float4 mj,
    float h0, float h1, float h2,
    const float* __restrict__ w, const float* __restrict__ b, float* x) {
  #pragma unroll
  for (int j = 0; j < 4; ++j) {
    float t = b[j];
    t += mi.x * w[0 * 4 + j]; t += mi.y * w[1 * 4 + j]; t += mi.z * w[2 * 4 + j];
    t += mj.x * w[3 * 4 + j]; t += mj.y * w[4 * 4 + j]; t += mj.z * w[5 * 4 + j];
    t += h0 * w[6 * 4 + j];  t += h1 * w[7 * 4 + j];  t += h2 * w[8 * 4 + j];
    x[j] = t;
  }
}

__device__ __forceinline__ void bn_coeff(const double* red, int n,
    const float* g, const float* be, float* s, float* t) {
  const double invE = 1.0 / (double)NEDGES;
  for (int c = 0; c < n; ++c) {
    double m = red[c] * invE;
    double var = red[n + c] * invE - m * m;
    double sc = (double)g[c] / sqrt(var + 1e-5);
    s[c] = (float)sc;
    t[c] = (float)((double)be[c] - m * sc);
  }
}

// ---------------- kz: pad-copy M, zero hist + accums ----------------
__global__ void __launch_bounds__(BLK) kz(const float* __restrict__ Min,
                                          float* __restrict__ M,
                                          int* __restrict__ hist,
                                          double* __restrict__ accs) {
  int tid = blockIdx.x * BLK + threadIdx.x;
  for (int v = tid; v < NNODES; v += STRIDE) {
    float4 m;
    m.x = Min[3 * v]; m.y = Min[3 * v + 1]; m.z = Min[3 * v + 2]; m.w = 0.f;
    *(float4*)(M + 4 * (size_t)v) = m;
    hist[v] = 0;
  }
  for (int i = tid; i < 3 * NB * 8; i += STRIDE) accs[i] = 0.0;
}

// ---------------- khr: histogram of dst, save rank (atomic return) ----------
__global__ void __launch_bounds__(BLK) khr(const int* __restrict__ dst,
                                           int* __restrict__ hist,
                                           int* __restrict__ rankpos) {
  int g = blockIdx.x * BLK + threadIdx.x;
  if (g >= NGROUP) return;
  int4 d4 = ((const int4*)dst)[g];
  int4 r;
  r.x = atomicAdd(&hist[d4.x], 1);
  r.y = atomicAdd(&hist[d4.y], 1);
  r.z = atomicAdd(&hist[d4.z], 1);
  r.w = atomicAdd(&hist[d4.w], 1);
  ((int4*)rankpos)[g] = r;
}

// ---------------- ksA: per-block sums of hist ----------------
__global__ void __launch_bounds__(256) ksA(const int* __restrict__ hist,
                                           int* __restrict__ bsum) {
  __shared__ int sm[256];
  int i = blockIdx.x * 256 + threadIdx.x;
  sm[threadIdx.x] = (i < NNODES) ? hist[i] : 0;
  __syncthreads();
  for (int o = 128; o > 0; o >>= 1) {
    if (threadIdx.x < o) sm[threadIdx.x] += sm[threadIdx.x + o];
    __syncthreads();
  }
  if (threadIdx.x == 0) bsum[blockIdx.x] = sm[0];
}

// ---------------- ksB: exclusive scan of the 391 block sums (1 block) -------
__global__ void __launch_bounds__(512) ksB(const int* __restrict__ bsum,
                                           int* __restrict__ bbase) {
  __shared__ int sm[512];
  int t = threadIdx.x;
  sm[t] = (t < NBLKN) ? bsum[t] : 0;
  __syncthreads();
  for (int o = 1; o < 512; o <<= 1) {
    int v = (t >= o) ? sm[t - o] : 0;
    __syncthreads();
    sm[t] += v;
    __syncthreads();
  }
  if (t < NBLKN) bbase[t] = (t == 0) ? 0 : sm[t - 1];
}

// ---------------- ksC: per-element offsets + dp fill ----------------
__global__ void __launch_bounds__(256) ksC(const int* __restrict__ hist,
                                           const int* __restrict__ bbase,
                                           int* __restrict__ off,
                                           int* __restrict__ dp) {
  __shared__ int sm[256];
  int t = threadIdx.x;
  int i = blockIdx.x * 256 + t;
  int v = (i < NNODES) ? hist[i] : 0;
  sm[t] = v;
  __syncthreads();
  for (int o = 1; o < 256; o <<= 1) {
    int u = (t >= o) ? sm[t - o] : 0;
    __syncthreads();
    sm[t] += u;
    __syncthreads();
  }
  if (i < NNODES) {
    int ex = bbase[blockIdx.x] + sm[t] - v;
    off[i] = ex;
    for (int e = ex; e < ex + v; ++e) dp[e] = i;   // CSR-order dst fill
  }
  if (i == 0) off[NNODES] = NEDGES;
}

// ---------------- kpk: pack dp groups as {base, 3x u8 deltas} ----------------
__global__ void __launch_bounds__(BLK) kpk(const int* __restrict__ dp,
                                           int2* __restrict__ dpp) {
  int g = blockIdx.x * BLK + threadIdx.x;
  if (g >= NGROUP) return;
  int4 d4 = ((const int4*)dp)[g];
  int2 o;
  o.x = d4.x;
  o.y = (d4.y - d4.x) | ((d4.z - d4.x) << 8) | ((d4.w - d4.x) << 16);
  dpp[g] = o;
}

// ---------------- kp1: pos[e] = off[dst]+rank (in-place), eperm scatter -----
__global__ void __launch_bounds__(BLK) kp1(const int* __restrict__ dst,
                                           const int* __restrict__ off,
                                           int* __restrict__ rankpos,
                                           int* __restrict__ eperm) {
  int g = blockIdx.x * BLK + threadIdx.x;
  if (g >= NGROUP) return;
  int4 d4 = ((const int4*)dst)[g];
  int4 r4 = ((int4*)rankpos)[g];
  int4 p4;
  p4.x = off[d4.x] + r4.x;
  p4.y = off[d4.y] + r4.y;
  p4.z = off[d4.z] + r4.z;
  p4.w = off[d4.w] + r4.w;
  int e = 4 * g;
  eperm[p4.x] = e; eperm[p4.y] = e + 1; eperm[p4.z] = e + 2; eperm[p4.w] = e + 3;
  ((int4*)rankpos)[g] = p4;   // rankpos now holds pos[e]
}

// ---------------- kp2: gather src/H into CSR order (H -> H4/edge) -----------
__global__ void __launch_bounds__(BLK) kp2(const int* __restrict__ src,
                                           const float* __restrict__ Hin,
                                           const int* __restrict__ eperm,
                                           int* __restrict__ sp,
                                           __half* __restrict__ Hp) {
  int g = blockIdx.x * BLK + threadIdx.x;
  if (g >= NGROUP) return;
  int4 e4 = ((const int4*)eperm)[g];
  int4 s4;
  s4.x = src[e4.x];
  s4.y = src[e4.y];
  s4.z = src[e4.z];
  s4.w = src[e4.w];
  ((int4*)sp)[g] = s4;
  int ee[4] = {e4.x, e4.y, e4.z, e4.w};
  H4* Hv = (H4*)Hp + 4 * (size_t)g;
  #pragma unroll
  for (int k = 0; k < 4; ++k) {
    size_t e3 = 3 * (size_t)ee[k];
    H4 o;
    o.h[0] = __float2half(Hin[e3]);
    o.h[1] = __float2half(Hin[e3 + 1]);
    o.h[2] = __float2half(Hin[e3 + 2]);
    o.h[3] = __half(0.0f);
    Hv[k] = o;
  }
}

// ---------------- K1: x = e_in @ W1 + b1; STORE x (fp16x4); stats of x ------
// Two 4-edge groups per thread (8 edges): double ILP on the gather-latency
// phase, half the wave count. xb so k2 never re-gathers M[src]/H.
__global__ void __launch_bounds__(BLK) k1(
    const float* __restrict__ M, const __half* __restrict__ H,
    __half* __restrict__ xb,
    const int* __restrict__ sp, const int2* __restrict__ dpp,
    const float* __restrict__ W1, const float* __restrict__ b1,
    double* __restrict__ acc1, double* __restrict__ acc2) {
  int t = blockIdx.x * BLK + threadIdx.x;
  if (blockIdx.x == 0)
    for (int i = threadIdx.x; i < NB * 8; i += BLK) acc2[i] = 0.0;

  float sx[4] = {0, 0, 0, 0}, sq[4] = {0, 0, 0, 0};
  int g0 = 2 * t;
  if (g0 < NGROUP) {
    #pragma unroll
    for (int u = 0; u < 2; ++u) {
      int g = g0 + u;
      int4 s4 = ((const int4*)sp)[g];
      int2 dg = dpp[g];
      int d0 = dg.x;
      int d1 = d0 + (dg.y & 255);
      int d2 = d0 + ((dg.y >> 8) & 255);
      int d3 = d0 + ((dg.y >> 16) & 255);
      const H4* Hv = (const H4*)H + 4 * (size_t)g;
      H4 h0 = Hv[0], h1 = Hv[1], h2 = Hv[2], h3 = Hv[3];
      float4 mi0 = *(const float4*)(M + 4 * (size_t)d0);
      float4 mj0 = *(const float4*)(M + 4 * (size_t)s4.x);
      float4 mi1 = *(const float4*)(M + 4 * (size_t)d1);
      float4 mj1 = *(const float4*)(M + 4 * (size_t)s4.y);
      float4 mi2 = *(const float4*)(M + 4 * (size_t)d2);
      float4 mj2 = *(const float4*)(M + 4 * (size_t)s4.z);
      float4 mi3 = *(const float4*)(M + 4 * (size_t)d3);
      float4 mj3 = *(const float4*)(M + 4 * (size_t)s4.w);
      float x[4][4];
      compute_x(mi0, mj0, __half2float(h0.h[0]), __half2float(h0.h[1]), __half2float(h0.h[2]), W1, b1, x[0]);
      compute_x(mi1, mj1, __half2float(h1.h[0]), __half2float(h1.h[1]), __half2float(h1.h[2]), W1, b1, x[1]);
      compute_x(mi2, mj2, __half2float(h2.h[0]), __half2float(h2.h[1]), __half2float(h2.h[2]), W1, b1, x[2]);
      compute_x(mi3, mj3, __half2float(h3.h[0]), __half2float(h3.h[1]), __half2float(h3.h[2]), W1, b1, x[3]);
      // round to fp16 (what k2 will read back); stats on the ROUNDED values
      H4* xv = (H4*)xb + 4 * (size_t)g;
      #pragma unroll
      for (int k = 0; k < 4; ++k) {
        H4 xo;
        #pragma unroll
        for (int j = 0; j < 4; ++j) {
          __half hx = __float2half(x[k][j]);
          xo.h[j] = hx;
          float xr = __half2float(hx);
          sx[j] += xr; sq[j] += xr * xr;
        }
        xv[k] = xo;
      }
    }
  }
  float vals[8] = {sx[0], sx[1], sx[2], sx[3], sq[0], sq[1], sq[2], sq[3]};
  block_stats_atomic<8>(vals, acc1 + (size_t)(blockIdx.x & (NB - 1)) * 8);
}

// ---------------- K2: Hn per edge (in place over Hp) + stats of z -----------
__global__ void __launch_bounds__(BLK) k2(
    const float* __restrict__ M, __half* __restrict__ Hn,
    const __half* __restrict__ xb, const int2* __restrict__ dpp,
    const float* __restrict__ g1, const float* __restrict__ be1,
    const float* __restrict__ W2, const float* __restrict__ b2,
    const float* __restrict__ V1, const float* __restrict__ vb1,
    const double* __restrict__ acc1, double* __restrict__ acc2,
    int isFinal,
    const float* __restrict__ OW1, const float* __restrict__ ob1,
    double* __restrict__ accF) {
  double red[8];
  bank_reduce<8>(acc1, red);
  float s1[4], t1[4];
  bn_coeff(red, 4, g1, be1, s1, t1);
  float sz[3] = {0, 0, 0}, szz[3] = {0, 0, 0}, sf[3] = {0, 0, 0}, sff[3] = {0, 0, 0};
  int g = blockIdx.x * BLK + threadIdx.x;
  if (g < NGROUP) {
    int2 dg = dpp[g];
    int dd[4];
    dd[0] = dg.x;
    dd[1] = dd[0] + (dg.y & 255);
    dd[2] = dd[0] + ((dg.y >> 8) & 255);
    dd[3] = dd[0] + ((dg.y >> 16) & 255);
    float4 mi[4];
    mi[0] = *(const float4*)(M + 4 * (size_t)dd[0]);
    mi[1] = *(const float4*)(M + 4 * (size_t)dd[1]);
    mi[2] = *(const float4*)(M + 4 * (size_t)dd[2]);
    mi[3] = *(const float4*)(M + 4 * (size_t)dd[3]);
    const H4* xv = (const H4*)xb + 4 * (size_t)g;
    H4* Hw = (H4*)Hn + 4 * (size_t)g;
    #pragma unroll
    for (int k = 0; k < 4; ++k) {
      H4 xh = xv[k];
      float y[4];
      #pragma unroll
      for (int j = 0; j < 4; ++j)
        y[j] = fmaxf(__half2float(xh.h[j]) * s1[j] + t1[j], 0.f);
      H4 ho;
      float hr[3];
      #pragma unroll
      for (int c = 0; c < 3; ++c) {
        float v = b2[c] + y[0] * W2[0 * 3 + c] + y[1] * W2[1 * 3 + c]
                        + y[2] * W2[2 * 3 + c] + y[3] * W2[3 * 3 + c];
        __half hv = __float2half(v);
        ho.h[c] = hv;
        hr[c] = __half2float(hv);   // rounded value: what k1/k3 will read back
      }
      ho.h[3] = __half(0.0f);
      Hw[k] = ho;
      #pragma unroll
      for (int c = 0; c < 3; ++c) {
        float z = vb1[c] + mi[k].x * V1[0 * 3 + c] + mi[k].y * V1[1 * 3 + c] + mi[k].z * V1[2 * 3 + c]
                         + hr[0] * V1[3 * 3 + c] + hr[1] * V1[4 * 3 + c] + hr[2] * V1[5 * 3 + c];
        sz[c] += z; szz[c] += z * z;
      }
      if (isFinal) {
        #pragma unroll
        for (int c = 0; c < 3; ++c) {
          float f = ob1[c] + hr[0] * OW1[0 * 3 + c] + hr[1] * OW1[1 * 3 + c] + hr[2] * OW1[2 * 3 + c];
          sf[c] += f; sff[c] += f * f;
        }
      }
    }
  }
  size_t bank = (size_t)(blockIdx.x & (NB - 1)) * 8;
  float v6[6] = {sz[0], sz[1], sz[2], szz[0], szz[1], szz[2]};
  block_stats_atomic<6>(v6, acc2 + bank);
  if (isFinal) {
    float v6b[6] = {sf[0], sf[1], sf[2], sff[0], sff[1], sff[2]};
    block_stats_atomic<6>(v6b, accF + bank);
  }
}

// ---------------- K3: node aggregation, 4 lanes per node; M IN PLACE --------
__global__ void __launch_bounds__(BLK) k3(
    float* __restrict__ M, const __half* __restrict__ Hn,
    const int* __restrict__ off,
    const float* __restrict__ V1, const float* __restrict__ vb1,
    const float* __restrict__ vg1, const float* __restrict__ vbe1,
    const float* __restrict__ V2, const float* __restrict__ vb2,
    const double* __restrict__ acc2, double* __restrict__ acc1) {
  double red[6];
  bank_reduce<6>(acc2, red);
  float s2[3], t2[3];
  bn_coeff(red, 3, vg1, vbe1, s2, t2);
  if (blockIdx.x == 0)
    for (int i = threadIdx.x; i < NB * 8; i += BLK) acc1[i] = 0.0;

  int idx = blockIdx.x * BLK + threadIdx.x;
  int v = idx >> 2, q = idx & 3;
  if (v >= NNODES) return;
  float4 mi = *(const float4*)(M + 4 * (size_t)v);
  // hoist the mi-dependent part of z out of the edge loop
  float zc[3];
  #pragma unroll
  for (int c = 0; c < 3; ++c)
    zc[c] = vb1[c] + mi.x * V1[0 * 3 + c] + mi.y * V1[1 * 3 + c] + mi.z * V1[2 * 3 + c];
  int e0 = off[v], e1 = off[v + 1];
  float a0 = 0.f, a1 = 0.f, a2v = 0.f;
  int cnt = 0;
  const H4* Hq = (const H4*)Hn;
  for (int e = e0 + q; e < e1; e += 4) {
    H4 hh = Hq[e];                       // one aligned 8B load per edge
    float h0 = __half2float(hh.h[0]), h1 = __half2float(hh.h[1]), h2 = __half2float(hh.h[2]);
    float y[3];
    #pragma unroll
    for (int c = 0; c < 3; ++c) {
      float z = zc[c] + h0 * V1[3 * 3 + c] + h1 * V1[4 * 3 + c] + h2 * V1[5 * 3 + c];
      y[c] = fmaxf(z * s2[c] + t2[c], 0.f);
    }
    a0  += y[0] * V2[0] + y[1] * V2[3] + y[2] * V2[6];
    a1  += y[0] * V2[1] + y[1] * V2[4] + y[2] * V2[7];
    a2v += y[0] * V2[2] + y[1] * V2[5] + y[2] * V2[8];
    ++cnt;
  }
  a0  += vb2[0] * (float)cnt;            // per-edge bias, hoisted
  a1  += vb2[1] * (float)cnt;
  a2v += vb2[2] * (float)cnt;
  a0  += __shfl_down(a0, 2, 4);  a0  += __shfl_down(a0, 1, 4);
  a1  += __shfl_down(a1, 2, 4);  a1  += __shfl_down(a1, 1, 4);
  a2v += __shfl_down(a2v, 2, 4); a2v += __shfl_down(a2v, 1, 4);
  if (q == 0) {
    float4 o; o.x = a0; o.y = a1; o.z = a2v; o.w = 0.f;
    *(float4*)(M + 4 * (size_t)v) = o;   // in place: only lanes of v read M[v]
  }
}

// ---------------- head: gather H via pos, streamed out writes ----------------
__global__ void __launch_bounds__(BLK) f2(
    const __half* __restrict__ H, const int* __restrict__ pos,
    const float* __restrict__ OW1, const float* __restrict__ ob1,
    const float* __restrict__ og, const float* __restrict__ obe,
    const float* __restrict__ OW2, const float* __restrict__ ob2,
    const double* __restrict__ accF, float* __restrict__ out) {
  double red[6];
  bank_reduce<6>(accF, red);
  float sF[3], tF[3];
  bn_coeff(red, 3, og, obe, sF, tF);
  int g = blockIdx.x * BLK + threadIdx.x;
  if (g >= NGROUP) return;
  int4 p4 = ((const int4*)pos)[g];
  int p[4] = {p4.x, p4.y, p4.z, p4.w};
  const H4* Hq = (const H4*)H;
  float2 o[4];
  #pragma unroll
  for (int k = 0; k < 4; ++k) {
    H4 hh = Hq[p[k]];                    // one aligned 8B gather per edge
    float h0 = __half2float(hh.h[0]), h1 = __half2float(hh.h[1]), h2 = __half2float(hh.h[2]);
    float y[3];
    #pragma unroll
    for (int c = 0; c < 3; ++c) {
      float f = ob1[c] + h0 * OW1[0 * 3 + c] + h1 * OW1[1 * 3 + c] + h2 * OW1[2 * 3 + c];
      y[c] = fmaxf(f * sF[c] + tF[c], 0.f);
    }
    float l0 = ob2[0] + y[0] * OW2[0] + y[1] * OW2[2] + y[2] * OW2[4];
    float l1 = ob2[1] + y[0] * OW2[1] + y[1] * OW2[3] + y[2] * OW2[5];
    float mx = fmaxf(l0, l1);
    float e0 = __expf(l0 - mx), e1 = __expf(l1 - mx);
    float inv = 1.f / (e0 + e1);
    o[k].x = e0 * inv; o[k].y = e1 * inv;
  }
  float4 oA, oB;
  oA.x = o[0].x; oA.y = o[0].y; oA.z = o[1].x; oA.w = o[1].y;
  oB.x = o[2].x; oB.y = o[2].y; oB.z = o[3].x; oB.w = o[3].y;
  ((float4*)out)[2 * (size_t)g] = oA;
  ((float4*)out)[2 * (size_t)g + 1] = oB;
}

extern "C" void kernel_launch(void* const* d_in, const int* in_sizes, int n_in,
                              void* d_out, int out_size, void* d_ws, size_t ws_size,
                              hipStream_t stream) {
  const float* M_in   = (const float*)d_in[0];
  const float* H_in   = (const float*)d_in[1];
  const int*   ei     = (const int*)d_in[2];
  const float* we_w1  = (const float*)d_in[3];
  const float* we_b1  = (const float*)d_in[4];
  const float* we_g1  = (const float*)d_in[5];
  const float* we_be1 = (const float*)d_in[6];
  const float* we_w2  = (const float*)d_in[7];
  const float* we_b2  = (const float*)d_in[8];
  const float* wv_w1  = (const float*)d_in[9];
  const float* wv_b1  = (const float*)d_in[10];
  const float* wv_g1  = (const float*)d_in[11];
  const float* wv_be1 = (const float*)d_in[12];
  const float* wv_w2  = (const float*)d_in[13];
  const float* wv_b2  = (const float*)d_in[14];
  const float* out_w1 = (const float*)d_in[15];
  const float* out_b1 = (const float*)d_in[16];
  const float* out_g  = (const float*)d_in[17];
  const float* out_be = (const float*)d_in[18];
  const float* out_w2 = (const float*)d_in[19];
  const float* out_b2 = (const float*)d_in[20];
  const int* src = ei;
  const int* dst = ei + NEDGES;

  float* ws = (float*)d_ws;
  float* M     = ws;                         // N*4 floats (in-place across layers)
  __half* Hp   = (__half*)(ws + 400000);     // E*4 halfs (H4/edge, in-place)
  __half* xb   = (__half*)(ws + 3600000);    // E*4 halfs staged x
  int* ib      = (int*)(ws + 6800000);       // int region
  int* sp      = ib;                         // E
  int* dp      = ib + 1600000;               // E (setup only; aliased as eperm)
  int* rankpos = ib + 3200000;               // E (rank, then pos; f2 reads)
  int2* dpp    = (int2*)(ib + 4800000);      // E/4 int2 = E/2 ints
  int* hist    = ib + 5600000;               // N
  int* off     = ib + 5700000;               // N+1
  int* bsum    = ib + 5800001;               // 400
  int* bbase   = ib + 5800401;               // 400 -> region end 5800801
  double* accs = (double*)(ws + 6800000 + 5800802);  // even float idx -> 8B-aligned
  double* acc1 = accs;
  double* acc2 = accs + NB * 8;
  double* accF = accs + 2 * NB * 8;
  int* eperm   = dp;   // alias: dp dead after kpk, eperm born in kp1

  // --- build CSR permutation (ws is re-poisoned between replays) ---
  kz<<<GRIDE, BLK, 0, stream>>>(M_in, M, hist, accs);
  khr<<<GRIDL, BLK, 0, stream>>>(dst, hist, rankpos);
  ksA<<<NBLKN, 256, 0, stream>>>(hist, bsum);
  ksB<<<1, 512, 0, stream>>>(bsum, bbase);
  ksC<<<NBLKN, 256, 0, stream>>>(hist, bbase, off, dp);
  kpk<<<GRIDL, BLK, 0, stream>>>(dp, dpp);
  kp1<<<GRIDL, BLK, 0, stream>>>(dst, off, rankpos, eperm);
  kp2<<<GRIDL, BLK, 0, stream>>>(src, H_in, eperm, sp, Hp);

  for (int l = 0; l < NLAYERS; ++l) {
    k1<<<GRIDL2, BLK, 0, stream>>>(M, Hp, xb, sp, dpp, we_w1, we_b1, acc1, acc2);
    k2<<<GRIDL, BLK, 0, stream>>>(M, Hp, xb, dpp, we_g1, we_be1,
                                  we_w2, we_b2, wv_w1, wv_b1, acc1, acc2,
                                  (l == NLAYERS - 1) ? 1 : 0, out_w1, out_b1, accF);
    if (l < NLAYERS - 1)
      k3<<<GRIDN4, BLK, 0, stream>>>(
          M, Hp, off, wv_w1, wv_b1, wv_g1, wv_be1, wv_w2, wv_b2, acc2, acc1);
  }
  f2<<<GRIDL, BLK, 0, stream>>>(Hp, rankpos, out_w1, out_b1, out_g, out_be,
                                out_w2, out_b2, accF, (float*)d_out);
}

// Round 6
// 1136.756 us; speedup vs baseline: 2.4321x; 1.0903x over previous
//
#include <hip/hip_runtime.h>
#include <hip/hip_fp16.h>
#include <math.h>

#define NNODES 100000
#define NEDGES 1600000
#define NGROUP (NEDGES / 4)    // 4-edge groups
#define NLAYERS 20
#define NB 256          // accumulator banks == BLK (keeps atomic chains ~6 deep)
#define BLK 256
#define GRIDE 1024                          // stride kernels (setup)
#define STRIDE (GRIDE * BLK)
#define GRIDL ((NGROUP + BLK - 1) / BLK)    // 1563: one 4-edge group per thread
#define NBLKN ((NNODES + 255) / 256)        // 391 blocks for node kernels
#define GRIDN4 ((NNODES * 4 + BLK - 1) / BLK)  // 4 lanes per node (k3)

struct __align__(8) H4 { __half h[4]; };    // 4 halfs, 8B load/store

// ---- block reduce of N float stats -> N parallel f64 atomics (one per lane) ----
// f32 wave butterflies (1 DS op per shuffle instead of 2 for f64); f64 from the
// 4 wave partials upward. Wave partial = tree sum of <=256 O(1) values: rel err
// ~1e-7 on the final 1.6M-element f64 total -- far below BN's sensitivity.
template<int N>
__device__ __forceinline__ void block_stats_atomic(const float* vals, double* base) {
  __shared__ float sm[8][4];
  int lane = threadIdx.x & 63, wid = threadIdx.x >> 6;
  __syncthreads();                  // guard back-to-back calls reusing sm
  #pragma unroll
  for (int n = 0; n < N; ++n) {
    float d = vals[n];
    #pragma unroll
    for (int o = 32; o > 0; o >>= 1) d += __shfl_down(d, o, 64);
    if (lane == 0) sm[n][wid] = d;
  }
  __syncthreads();
  if (threadIdx.x < N) {
    double s = (double)sm[threadIdx.x][0] + (double)sm[threadIdx.x][1]
             + (double)sm[threadIdx.x][2] + (double)sm[threadIdx.x][3];
    atomicAdd(base + threadIdx.x, s);
  }
}

// ---- prologue: reduce NB banks via per-wave shuffle butterfly (1 sync) ----
template<int NS>
__device__ __forceinline__ void bank_reduce(const double* __restrict__ acc, double* res) {
  __shared__ double part[4][8];
  int t = threadIdx.x;               // 256 threads = 4 waves x 64 = NB banks
  double v[NS];
  #pragma unroll
  for (int s = 0; s < NS; ++s) v[s] = acc[t * 8 + s];
  #pragma unroll
  for (int o = 32; o > 0; o >>= 1)
    #pragma unroll
    for (int s = 0; s < NS; ++s) v[s] += __shfl_down(v[s], o, 64);
  if ((t & 63) == 0) {
    int w = t >> 6;
    #pragma unroll
    for (int s = 0; s < NS; ++s) part[w][s] = v[s];
  }
  __syncthreads();
  #pragma unroll
  for (int s = 0; s < NS; ++s) res[s] = part[0][s] + part[1][s] + part[2][s] + part[3][s];
}

// x = [mi, mj, h] @ W1 + b1  (9->4)
__device__ __forceinline__ void compute_x(const float4 mi, const float4 mj,
    float h0, float h1, float h2,
    const float* __restrict__ w, const float* __restrict__ b, float* x) {
  #pragma unroll
  for (int j = 0; j < 4; ++j) {
    float t = b[j];
    t += mi.x * w[0 * 4 + j]; t += mi.y * w[1 * 4 + j]; t += mi.z * w[2 * 4 + j];
    t += mj.x * w[3 * 4 + j]; t += mj.y * w[4 * 4 + j]; t += mj.z * w[5 * 4 + j];
    t += h0 * w[6 * 4 + j];  t += h1 * w[7 * 4 + j];  t += h2 * w[8 * 4 + j];
    x[j] = t;
  }
}

__device__ __forceinline__ void bn_coeff(const double* red, int n,
    const float* g, const float* be, float* s, float* t) {
  const double invE = 1.0 / (double)NEDGES;
  for (int c = 0; c < n; ++c) {
    double m = red[c] * invE;
    double var = red[n + c] * invE - m * m;
    double sc = (double)g[c] / sqrt(var + 1e-5);
    s[c] = (float)sc;
    t[c] = (float)((double)be[c] - m * sc);
  }
}

// ---------------- kz: pad-copy M, zero hist + accums ----------------
__global__ void __launch_bounds__(BLK) kz(const float* __restrict__ Min,
                                          float* __restrict__ M,
                                          int* __restrict__ hist,
                                          double* __restrict__ accs) {
  int tid = blockIdx.x * BLK + threadIdx.x;
  for (int v = tid; v < NNODES; v += STRIDE) {
    float4 m;
    m.x = Min[3 * v]; m.y = Min[3 * v + 1]; m.z = Min[3 * v + 2]; m.w = 0.f;
    *(float4*)(M + 4 * (size_t)v) = m;
    hist[v] = 0;
  }
  for (int i = tid; i < 3 * NB * 8; i += STRIDE) accs[i] = 0.0;
}

// ---------------- khr: histogram of dst, save rank (atomic return) ----------
__global__ void __launch_bounds__(BLK) khr(const int* __restrict__ dst,
                                           int* __restrict__ hist,
                                           int* __restrict__ rankpos) {
  int g = blockIdx.x * BLK + threadIdx.x;
  if (g >= NGROUP) return;
  int4 d4 = ((const int4*)dst)[g];
  int4 r;
  r.x = atomicAdd(&hist[d4.x], 1);
  r.y = atomicAdd(&hist[d4.y], 1);
  r.z = atomicAdd(&hist[d4.z], 1);
  r.w = atomicAdd(&hist[d4.w], 1);
  ((int4*)rankpos)[g] = r;
}

// ---------------- ksA: per-block sums of hist ----------------
__global__ void __launch_bounds__(256) ksA(const int* __restrict__ hist,
                                           int* __restrict__ bsum) {
  __shared__ int sm[256];
  int i = blockIdx.x * 256 + threadIdx.x;
  sm[threadIdx.x] = (i < NNODES) ? hist[i] : 0;
  __syncthreads();
  for (int o = 128; o > 0; o >>= 1) {
    if (threadIdx.x < o) sm[threadIdx.x] += sm[threadIdx.x + o];
    __syncthreads();
  }
  if (threadIdx.x == 0) bsum[blockIdx.x] = sm[0];
}

// ---------------- ksB: exclusive scan of the 391 block sums (1 block) -------
__global__ void __launch_bounds__(512) ksB(const int* __restrict__ bsum,
                                           int* __restrict__ bbase) {
  __shared__ int sm[512];
  int t = threadIdx.x;
  sm[t] = (t < NBLKN) ? bsum[t] : 0;
  __syncthreads();
  for (int o = 1; o < 512; o <<= 1) {
    int v = (t >= o) ? sm[t - o] : 0;
    __syncthreads();
    sm[t] += v;
    __syncthreads();
  }
  if (t < NBLKN) bbase[t] = (t == 0) ? 0 : sm[t - 1];
}

// ---------------- ksC: per-element offsets + dp fill ----------------
__global__ void __launch_bounds__(256) ksC(const int* __restrict__ hist,
                                           const int* __restrict__ bbase,
                                           int* __restrict__ off,
                                           int* __restrict__ dp) {
  __shared__ int sm[256];
  int t = threadIdx.x;
  int i = blockIdx.x * 256 + t;
  int v = (i < NNODES) ? hist[i] : 0;
  sm[t] = v;
  __syncthreads();
  for (int o = 1; o < 256; o <<= 1) {
    int u = (t >= o) ? sm[t - o] : 0;
    __syncthreads();
    sm[t] += u;
    __syncthreads();
  }
  if (i < NNODES) {
    int ex = bbase[blockIdx.x] + sm[t] - v;
    off[i] = ex;
    for (int e = ex; e < ex + v; ++e) dp[e] = i;   // CSR-order dst fill
  }
  if (i == 0) off[NNODES] = NEDGES;
}

// ---------------- kpk: pack dp groups as {base, 3x u8 deltas} ----------------
__global__ void __launch_bounds__(BLK) kpk(const int* __restrict__ dp,
                                           int2* __restrict__ dpp) {
  int g = blockIdx.x * BLK + threadIdx.x;
  if (g >= NGROUP) return;
  int4 d4 = ((const int4*)dp)[g];
  int2 o;
  o.x = d4.x;
  o.y = (d4.y - d4.x) | ((d4.z - d4.x) << 8) | ((d4.w - d4.x) << 16);
  dpp[g] = o;
}

// ---------------- kp1: pos[e] = off[dst]+rank (in-place), eperm scatter -----
__global__ void __launch_bounds__(BLK) kp1(const int* __restrict__ dst,
                                           const int* __restrict__ off,
                                           int* __restrict__ rankpos,
                                           int* __restrict__ eperm) {
  int g = blockIdx.x * BLK + threadIdx.x;
  if (g >= NGROUP) return;
  int4 d4 = ((const int4*)dst)[g];
  int4 r4 = ((int4*)rankpos)[g];
  int4 p4;
  p4.x = off[d4.x] + r4.x;
  p4.y = off[d4.y] + r4.y;
  p4.z = off[d4.z] + r4.z;
  p4.w = off[d4.w] + r4.w;
  int e = 4 * g;
  eperm[p4.x] = e; eperm[p4.y] = e + 1; eperm[p4.z] = e + 2; eperm[p4.w] = e + 3;
  ((int4*)rankpos)[g] = p4;   // rankpos now holds pos[e]
}

// ---------------- kp2: gather src/H into CSR order (H -> fp16) --------------
__global__ void __launch_bounds__(BLK) kp2(const int* __restrict__ src,
                                           const float* __restrict__ Hin,
                                           const int* __restrict__ eperm,
                                           int* __restrict__ sp,
                                           __half* __restrict__ Hp) {
  int g = blockIdx.x * BLK + threadIdx.x;
  if (g >= NGROUP) return;
  int4 e4 = ((const int4*)eperm)[g];
  int4 s4;
  s4.x = src[e4.x];
  s4.y = src[e4.y];
  s4.z = src[e4.z];
  s4.w = src[e4.w];
  __half hh[12];
  int ee[4] = {e4.x, e4.y, e4.z, e4.w};
  #pragma unroll
  for (int k = 0; k < 4; ++k) {
    size_t e3 = 3 * (size_t)ee[k];
    hh[3 * k]     = __float2half(Hin[e3]);
    hh[3 * k + 1] = __float2half(Hin[e3 + 1]);
    hh[3 * k + 2] = __float2half(Hin[e3 + 2]);
  }
  ((int4*)sp)[g] = s4;
  H4* Hv = (H4*)(Hp + 12 * (size_t)g);
  H4 a, b, c;
  #pragma unroll
  for (int i = 0; i < 4; ++i) { a.h[i] = hh[i]; b.h[i] = hh[4 + i]; c.h[i] = hh[8 + i]; }
  Hv[0] = a; Hv[1] = b; Hv[2] = c;
}

// ---------------- K1: x = e_in @ W1 + b1; STORE x (fp16x4); stats of x ------
// x is staged so k2 never re-gathers M[src] (the only random loads in the
// layer loop) nor re-reads H nor recomputes the 9->4 matvec.
__global__ void __launch_bounds__(BLK) k1(
    const float* __restrict__ M, const __half* __restrict__ H,
    __half* __restrict__ xb,
    const int* __restrict__ sp, const int2* __restrict__ dpp,
    const float* __restrict__ W1, const float* __restrict__ b1,
    double* __restrict__ acc1, double* __restrict__ acc2) {
  int g = blockIdx.x * BLK + threadIdx.x;
  if (blockIdx.x == 0)
    for (int i = threadIdx.x; i < NB * 8; i += BLK) acc2[i] = 0.0;

  float sx[4] = {0, 0, 0, 0}, sq[4] = {0, 0, 0, 0};
  if (g < NGROUP) {
    int4 s4 = ((const int4*)sp)[g];
    int2 dppg = dpp[g];
    int d0 = dppg.x;
    int d1 = d0 + (dppg.y & 255);
    int d2 = d0 + ((dppg.y >> 8) & 255);
    int d3 = d0 + ((dppg.y >> 16) & 255);
    const H4* Hv = (const H4*)(H + 12 * (size_t)g);
    H4 a = Hv[0], b = Hv[1], c = Hv[2];
    float hf[12];
    #pragma unroll
    for (int i = 0; i < 4; ++i) {
      hf[i] = __half2float(a.h[i]); hf[4 + i] = __half2float(b.h[i]); hf[8 + i] = __half2float(c.h[i]);
    }
    float4 mi0 = *(const float4*)(M + 4 * (size_t)d0);
    float4 mj0 = *(const float4*)(M + 4 * (size_t)s4.x);
    float4 mi1 = *(const float4*)(M + 4 * (size_t)d1);
    float4 mj1 = *(const float4*)(M + 4 * (size_t)s4.y);
    float4 mi2 = *(const float4*)(M + 4 * (size_t)d2);
    float4 mj2 = *(const float4*)(M + 4 * (size_t)s4.z);
    float4 mi3 = *(const float4*)(M + 4 * (size_t)d3);
    float4 mj3 = *(const float4*)(M + 4 * (size_t)s4.w);
    float x[4][4];
    compute_x(mi0, mj0, hf[0], hf[1], hf[2],  W1, b1, x[0]);
    compute_x(mi1, mj1, hf[3], hf[4], hf[5],  W1, b1, x[1]);
    compute_x(mi2, mj2, hf[6], hf[7], hf[8],  W1, b1, x[2]);
    compute_x(mi3, mj3, hf[9], hf[10], hf[11], W1, b1, x[3]);
    // round to fp16 (what k2 will read back); stats on the ROUNDED values
    H4* xv = (H4*)xb + 4 * (size_t)g;
    #pragma unroll
    for (int k = 0; k < 4; ++k) {
      H4 xo;
      #pragma unroll
      for (int j = 0; j < 4; ++j) {
        __half hx = __float2half(x[k][j]);
        xo.h[j] = hx;
        float xr = __half2float(hx);
        sx[j] += xr; sq[j] += xr * xr;
      }
      xv[k] = xo;
    }
  }
  float vals[8] = {sx[0], sx[1], sx[2], sx[3], sq[0], sq[1], sq[2], sq[3]};
  block_stats_atomic<8>(vals, acc1 + (size_t)(blockIdx.x & (NB - 1)) * 8);
}

// ---------------- K2: Hn per edge (IN PLACE over H) + stats of z ------------
// Pure streaming: reads staged x + near-sequential M[dst]; no sp/H/mj.
__global__ void __launch_bounds__(BLK) k2(
    const float* __restrict__ M, __half* __restrict__ Hn,
    const __half* __restrict__ xb, const int2* __restrict__ dpp,
    const float* __restrict__ g1, const float* __restrict__ be1,
    const float* __restrict__ W2, const float* __restrict__ b2,
    const float* __restrict__ V1, const float* __restrict__ vb1,
    const double* __restrict__ acc1, double* __restrict__ acc2,
    int isFinal,
    const float* __restrict__ OW1, const float* __restrict__ ob1,
    double* __restrict__ accF) {
  double red[8];
  bank_reduce<8>(acc1, red);
  float s1[4], t1[4];
  bn_coeff(red, 4, g1, be1, s1, t1);
  float sz[3] = {0, 0, 0}, szz[3] = {0, 0, 0}, sf[3] = {0, 0, 0}, sff[3] = {0, 0, 0};
  int g = blockIdx.x * BLK + threadIdx.x;
  if (g < NGROUP) {
    int2 dppg = dpp[g];
    int dd[4];
    dd[0] = dppg.x;
    dd[1] = dd[0] + (dppg.y & 255);
    dd[2] = dd[0] + ((dppg.y >> 8) & 255);
    dd[3] = dd[0] + ((dppg.y >> 16) & 255);
    float4 mi[4];
    mi[0] = *(const float4*)(M + 4 * (size_t)dd[0]);
    mi[1] = *(const float4*)(M + 4 * (size_t)dd[1]);
    mi[2] = *(const float4*)(M + 4 * (size_t)dd[2]);
    mi[3] = *(const float4*)(M + 4 * (size_t)dd[3]);
    const H4* xv = (const H4*)xb + 4 * (size_t)g;
    __half hh[12];
    #pragma unroll
    for (int k = 0; k < 4; ++k) {
      H4 xh = xv[k];
      float y[4];
      #pragma unroll
      for (int j = 0; j < 4; ++j)
        y[j] = fmaxf(__half2float(xh.h[j]) * s1[j] + t1[j], 0.f);
      float hr[3];
      #pragma unroll
      for (int c = 0; c < 3; ++c) {
        float v = b2[c] + y[0] * W2[0 * 3 + c] + y[1] * W2[1 * 3 + c]
                        + y[2] * W2[2 * 3 + c] + y[3] * W2[3 * 3 + c];
        __half hv = __float2half(v);
        hh[3 * k + c] = hv;
        hr[c] = __half2float(hv);   // rounded value: what k1/k3 will read back
      }
      #pragma unroll
      for (int c = 0; c < 3; ++c) {
        float z = vb1[c] + mi[k].x * V1[0 * 3 + c] + mi[k].y * V1[1 * 3 + c] + mi[k].z * V1[2 * 3 + c]
                         + hr[0] * V1[3 * 3 + c] + hr[1] * V1[4 * 3 + c] + hr[2] * V1[5 * 3 + c];
        sz[c] += z; szz[c] += z * z;
      }
      if (isFinal) {
        #pragma unroll
        for (int c = 0; c < 3; ++c) {
          float f = ob1[c] + hr[0] * OW1[0 * 3 + c] + hr[1] * OW1[1 * 3 + c] + hr[2] * OW1[2 * 3 + c];
          sf[c] += f; sff[c] += f * f;
        }
      }
    }
    H4* Hw = (H4*)(Hn + 12 * (size_t)g);
    H4 oA, oB, oC;
    #pragma unroll
    for (int i = 0; i < 4; ++i) { oA.h[i] = hh[i]; oB.h[i] = hh[4 + i]; oC.h[i] = hh[8 + i]; }
    Hw[0] = oA; Hw[1] = oB; Hw[2] = oC;
  }
  size_t bank = (size_t)(blockIdx.x & (NB - 1)) * 8;
  float v6[6] = {sz[0], sz[1], sz[2], szz[0], szz[1], szz[2]};
  block_stats_atomic<6>(v6, acc2 + bank);
  if (isFinal) {
    float v6b[6] = {sf[0], sf[1], sf[2], sff[0], sff[1], sff[2]};
    block_stats_atomic<6>(v6b, accF + bank);
  }
}

// ---------------- K3: node aggregation, 4 lanes per node; M IN PLACE --------
// k3 reads only M[v] of its own node, so updating M in place is race-free.
__global__ void __launch_bounds__(BLK) k3(
    float* __restrict__ M, const __half* __restrict__ Hn,
    const int* __restrict__ off,
    const float* __restrict__ V1, const float* __restrict__ vb1,
    const float* __restrict__ vg1, const float* __restrict__ vbe1,
    const float* __restrict__ V2, const float* __restrict__ vb2,
    const double* __restrict__ acc2, double* __restrict__ acc1) {
  double red[6];
  bank_reduce<6>(acc2, red);
  float s2[3], t2[3];
  bn_coeff(red, 3, vg1, vbe1, s2, t2);
  if (blockIdx.x == 0)
    for (int i = threadIdx.x; i < NB * 8; i += BLK) acc1[i] = 0.0;

  int idx = blockIdx.x * BLK + threadIdx.x;
  int v = idx >> 2, q = idx & 3;
  if (v >= NNODES) return;
  float4 mi = *(const float4*)(M + 4 * (size_t)v);
  // hoist the mi-dependent prefix of z (same association order -> bit-identical)
  float zc[3];
  #pragma unroll
  for (int c = 0; c < 3; ++c)
    zc[c] = vb1[c] + mi.x * V1[0 * 3 + c] + mi.y * V1[1 * 3 + c] + mi.z * V1[2 * 3 + c];
  int e0 = off[v], e1 = off[v + 1];
  float a0 = 0.f, a1 = 0.f, a2v = 0.f;
  int cnt = 0;
  for (int e = e0 + q; e < e1; e += 4) {
    size_t e3 = 3 * (size_t)e;
    float h0 = __half2float(Hn[e3]), h1 = __half2float(Hn[e3 + 1]), h2 = __half2float(Hn[e3 + 2]);
    float y[3];
    #pragma unroll
    for (int c = 0; c < 3; ++c) {
      float z = zc[c] + h0 * V1[3 * 3 + c] + h1 * V1[4 * 3 + c] + h2 * V1[5 * 3 + c];
      y[c] = fmaxf(z * s2[c] + t2[c], 0.f);
    }
    a0  += y[0] * V2[0] + y[1] * V2[3] + y[2] * V2[6];
    a1  += y[0] * V2[1] + y[1] * V2[4] + y[2] * V2[7];
    a2v += y[0] * V2[2] + y[1] * V2[5] + y[2] * V2[8];
    ++cnt;
  }
  a0  += vb2[0] * (float)cnt;            // per-edge bias, hoisted
  a1  += vb2[1] * (float)cnt;
  a2v += vb2[2] * (float)cnt;
  a0  += __shfl_down(a0, 2, 4);  a0  += __shfl_down(a0, 1, 4);
  a1  += __shfl_down(a1, 2, 4);  a1  += __shfl_down(a1, 1, 4);
  a2v += __shfl_down(a2v, 2, 4); a2v += __shfl_down(a2v, 1, 4);
  if (q == 0) {
    float4 o; o.x = a0; o.y = a1; o.z = a2v; o.w = 0.f;
    *(float4*)(M + 4 * (size_t)v) = o;
  }
}

// ---------------- head: gather H via pos, streamed out writes ----------------
__global__ void __launch_bounds__(BLK) f2(
    const __half* __restrict__ H, const int* __restrict__ pos,
    const float* __restrict__ OW1, const float* __restrict__ ob1,
    const float* __restrict__ og, const float* __restrict__ obe,
    const float* __restrict__ OW2, const float* __restrict__ ob2,
    const double* __restrict__ accF, float* __restrict__ out) {
  double red[6];
  bank_reduce<6>(accF, red);
  float sF[3], tF[3];
  bn_coeff(red, 3, og, obe, sF, tF);
  int g = blockIdx.x * BLK + threadIdx.x;
  if (g >= NGROUP) return;
  int4 p4 = ((const int4*)pos)[g];
  int p[4] = {p4.x, p4.y, p4.z, p4.w};
  float2 o[4];
  #pragma unroll
  for (int k = 0; k < 4; ++k) {
    size_t p3 = 3 * (size_t)p[k];
    float h0 = __half2float(H[p3]), h1 = __half2float(H[p3 + 1]), h2 = __half2float(H[p3 + 2]);
    float y[3];
    #pragma unroll
    for (int c = 0; c < 3; ++c) {
      float f = ob1[c] + h0 * OW1[0 * 3 + c] + h1 * OW1[1 * 3 + c] + h2 * OW1[2 * 3 + c];
      y[c] = fmaxf(f * sF[c] + tF[c], 0.f);
    }
    float l0 = ob2[0] + y[0] * OW2[0] + y[1] * OW2[2] + y[2] * OW2[4];
    float l1 = ob2[1] + y[0] * OW2[1] + y[1] * OW2[3] + y[2] * OW2[5];
    float mx = fmaxf(l0, l1);
    float e0 = __expf(l0 - mx), e1 = __expf(l1 - mx);
    float inv = 1.f / (e0 + e1);
    o[k].x = e0 * inv; o[k].y = e1 * inv;
  }
  float4 oA, oB;
  oA.x = o[0].x; oA.y = o[0].y; oA.z = o[1].x; oA.w = o[1].y;
  oB.x = o[2].x; oB.y = o[2].y; oB.z = o[3].x; oB.w = o[3].y;
  ((float4*)out)[2 * (size_t)g] = oA;
  ((float4*)out)[2 * (size_t)g + 1] = oB;
}

extern "C" void kernel_launch(void* const* d_in, const int* in_sizes, int n_in,
                              void* d_out, int out_size, void* d_ws, size_t ws_size,
                              hipStream_t stream) {
  const float* M_in   = (const float*)d_in[0];
  const float* H_in   = (const float*)d_in[1];
  const int*   ei     = (const int*)d_in[2];
  const float* we_w1  = (const float*)d_in[3];
  const float* we_b1  = (const float*)d_in[4];
  const float* we_g1  = (const float*)d_in[5];
  const float* we_be1 = (const float*)d_in[6];
  const float* we_w2  = (const float*)d_in[7];
  const float* we_b2  = (const float*)d_in[8];
  const float* wv_w1  = (const float*)d_in[9];
  const float* wv_b1  = (const float*)d_in[10];
  const float* wv_g1  = (const float*)d_in[11];
  const float* wv_be1 = (const float*)d_in[12];
  const float* wv_w2  = (const float*)d_in[13];
  const float* wv_b2  = (const float*)d_in[14];
  const float* out_w1 = (const float*)d_in[15];
  const float* out_b1 = (const float*)d_in[16];
  const float* out_g  = (const float*)d_in[17];
  const float* out_be = (const float*)d_in[18];
  const float* out_w2 = (const float*)d_in[19];
  const float* out_b2 = (const float*)d_in[20];
  const int* src = ei;
  const int* dst = ei + NEDGES;

  float* ws = (float*)d_ws;
  float* M    = ws;                          // N*4 floats (in-place across layers)
  __half* Hp  = (__half*)(ws + 400000);      // E*3 halfs (single buffer, in-place)
  __half* xb  = (__half*)(ws + 2800000);     // E*4 halfs staged x (16B-aligned)
  int* ib      = (int*)(ws + 6000000);       // 16B-aligned int region
  int* sp      = ib;                         // E
  int* dp      = ib + 1600000;               // E (CSR dst, setup only)
  int* rankpos = ib + 3200000;               // E (rank, then pos)
  int2* dpp    = (int2*)(ib + 4800000);      // E/4 int2 = E/2 ints
  int* hist    = ib + 5600000;               // N
  int* off     = ib + 5700000;               // N+1
  int* bsum    = ib + 5800001;               // 400
  int* bbase   = ib + 5800401;               // 400
  double* accs = (double*)(ws + 6000000 + 5800802);  // even float idx -> 8B-aligned
  double* acc1 = accs;
  double* acc2 = accs + NB * 8;
  double* accF = accs + 2 * NB * 8;
  int* eperm   = dp;   // alias: dp dead after kpk, eperm born in kp1

  // --- build CSR permutation (ws is re-poisoned between replays) ---
  kz<<<GRIDE, BLK, 0, stream>>>(M_in, M, hist, accs);
  khr<<<GRIDL, BLK, 0, stream>>>(dst, hist, rankpos);
  ksA<<<NBLKN, 256, 0, stream>>>(hist, bsum);
  ksB<<<1, 512, 0, stream>>>(bsum, bbase);
  ksC<<<NBLKN, 256, 0, stream>>>(hist, bbase, off, dp);
  kpk<<<GRIDL, BLK, 0, stream>>>(dp, dpp);
  kp1<<<GRIDL, BLK, 0, stream>>>(dst, off, rankpos, eperm);
  kp2<<<GRIDL, BLK, 0, stream>>>(src, H_in, eperm, sp, Hp);

  for (int l = 0; l < NLAYERS; ++l) {
    k1<<<GRIDL, BLK, 0, stream>>>(M, Hp, xb, sp, dpp, we_w1, we_b1, acc1, acc2);
    k2<<<GRIDL, BLK, 0, stream>>>(M, Hp, xb, dpp, we_g1, we_be1,
                                  we_w2, we_b2, wv_w1, wv_b1, acc1, acc2,
                                  (l == NLAYERS - 1) ? 1 : 0, out_w1, out_b1, accF);
    if (l < NLAYERS - 1)
      k3<<<GRIDN4, BLK, 0, stream>>>(
          M, Hp, off, wv_w1, wv_b1, wv_g1, wv_be1, wv_w2, wv_b2, acc2, acc1);
  }
  f2<<<GRIDL, BLK, 0, stream>>>(Hp, rankpos, out_w1, out_b1, out_g, out_be,
                                out_w2, out_b2, accF, (float*)d_out);
}

// Round 7
// 1070.707 us; speedup vs baseline: 2.5822x; 1.0617x over previous
//
#include <hip/hip_runtime.h>
#include <hip/hip_fp16.h>
#include <math.h>

#define NNODES 100000
#define NEDGES 1600000
#define NGROUP (NEDGES / 4)    // 4-edge groups
#define NLAYERS 20
#define NB 256          // accumulator banks == BLK (keeps atomic chains ~6 deep)
#define BLK 256
#define GRIDE 1024                          // stride kernels (setup)
#define STRIDE (GRIDE * BLK)
#define GRIDL ((NGROUP + BLK - 1) / BLK)    // 1563: one 4-edge group per thread
#define GRIDR 1024                          // exact-residency grid (4 blk/CU x 256 CU)
#define NBLKN ((NNODES + 255) / 256)        // 391 blocks for node kernels
#define GRIDN4 ((NNODES * 4 + BLK - 1) / BLK)  // 4 lanes per node (k3)

struct __align__(8) H4 { __half h[4]; };    // 4 halfs, 8B load/store

// ---- block reduce of N float stats -> N parallel f64 atomics (one per lane) ----
// f32 wave butterflies (1 DS op per shuffle instead of 2 for f64); f64 from the
// 4 wave partials upward.
template<int N>
__device__ __forceinline__ void block_stats_atomic(const float* vals, double* base) {
  __shared__ float sm[8][4];
  int lane = threadIdx.x & 63, wid = threadIdx.x >> 6;
  __syncthreads();                  // guard back-to-back calls reusing sm
  #pragma unroll
  for (int n = 0; n < N; ++n) {
    float d = vals[n];
    #pragma unroll
    for (int o = 32; o > 0; o >>= 1) d += __shfl_down(d, o, 64);
    if (lane == 0) sm[n][wid] = d;
  }
  __syncthreads();
  if (threadIdx.x < N) {
    double s = (double)sm[threadIdx.x][0] + (double)sm[threadIdx.x][1]
             + (double)sm[threadIdx.x][2] + (double)sm[threadIdx.x][3];
    atomicAdd(base + threadIdx.x, s);
  }
}

// ---- prologue: reduce NB banks via per-wave shuffle butterfly (1 sync) ----
template<int NS>
__device__ __forceinline__ void bank_reduce(const double* __restrict__ acc, double* res) {
  __shared__ double part[4][8];
  int t = threadIdx.x;               // 256 threads = 4 waves x 64 = NB banks
  double v[NS];
  #pragma unroll
  for (int s = 0; s < NS; ++s) v[s] = acc[t * 8 + s];
  #pragma unroll
  for (int o = 32; o > 0; o >>= 1)
    #pragma unroll
    for (int s = 0; s < NS; ++s) v[s] += __shfl_down(v[s], o, 64);
  if ((t & 63) == 0) {
    int w = t >> 6;
    #pragma unroll
    for (int s = 0; s < NS; ++s) part[w][s] = v[s];
  }
  __syncthreads();
  #pragma unroll
  for (int s = 0; s < NS; ++s) res[s] = part[0][s] + part[1][s] + part[2][s] + part[3][s];
}

// x = [mi, mj, h] @ W1 + b1  (9->4)
__device__ __forceinline__ void compute_x(const float4 mi, const float4 mj,
    float h0, float h1, float h2,
    const float* __restrict__ w, const float* __restrict__ b, float* x) {
  #pragma unroll
  for (int j = 0; j < 4; ++j) {
    float t = b[j];
    t += mi.x * w[0 * 4 + j]; t += mi.y * w[1 * 4 + j]; t += mi.z * w[2 * 4 + j];
    t += mj.x * w[3 * 4 + j]; t += mj.y * w[4 * 4 + j]; t += mj.z * w[5 * 4 + j];
    t += h0 * w[6 * 4 + j];  t += h1 * w[7 * 4 + j];  t += h2 * w[8 * 4 + j];
    x[j] = t;
  }
}

__device__ __forceinline__ void bn_coeff(const double* red, int n,
    const float* g, const float* be, float* s, float* t) {
  const double invE = 1.0 / (double)NEDGES;
  for (int c = 0; c < n; ++c) {
    double m = red[c] * invE;
    double var = red[n + c] * invE - m * m;
    double sc = (double)g[c] / sqrt(var + 1e-5);
    s[c] = (float)sc;
    t[c] = (float)((double)be[c] - m * sc);
  }
}

// ---------------- kz: pad-copy M, zero hist + accums ----------------
__global__ void __launch_bounds__(BLK) kz(const float* __restrict__ Min,
                                          float* __restrict__ M,
                                          int* __restrict__ hist,
                                          double* __restrict__ accs) {
  int tid = blockIdx.x * BLK + threadIdx.x;
  for (int v = tid; v < NNODES; v += STRIDE) {
    float4 m;
    m.x = Min[3 * v]; m.y = Min[3 * v + 1]; m.z = Min[3 * v + 2]; m.w = 0.f;
    *(float4*)(M + 4 * (size_t)v) = m;
    hist[v] = 0;
  }
  for (int i = tid; i < 3 * NB * 8; i += STRIDE) accs[i] = 0.0;
}

// ---------------- khr: histogram of dst, save rank (atomic return) ----------
__global__ void __launch_bounds__(BLK) khr(const int* __restrict__ dst,
                                           int* __restrict__ hist,
                                           int* __restrict__ rankpos) {
  int g = blockIdx.x * BLK + threadIdx.x;
  if (g >= NGROUP) return;
  int4 d4 = ((const int4*)dst)[g];
  int4 r;
  r.x = atomicAdd(&hist[d4.x], 1);
  r.y = atomicAdd(&hist[d4.y], 1);
  r.z = atomicAdd(&hist[d4.z], 1);
  r.w = atomicAdd(&hist[d4.w], 1);
  ((int4*)rankpos)[g] = r;
}

// ---------------- ksA: per-block sums of hist ----------------
__global__ void __launch_bounds__(256) ksA(const int* __restrict__ hist,
                                           int* __restrict__ bsum) {
  __shared__ int sm[256];
  int i = blockIdx.x * 256 + threadIdx.x;
  sm[threadIdx.x] = (i < NNODES) ? hist[i] : 0;
  __syncthreads();
  for (int o = 128; o > 0; o >>= 1) {
    if (threadIdx.x < o) sm[threadIdx.x] += sm[threadIdx.x + o];
    __syncthreads();
  }
  if (threadIdx.x == 0) bsum[blockIdx.x] = sm[0];
}

// ---------------- ksB: exclusive scan of the 391 block sums (1 block) -------
__global__ void __launch_bounds__(512) ksB(const int* __restrict__ bsum,
                                           int* __restrict__ bbase) {
  __shared__ int sm[512];
  int t = threadIdx.x;
  sm[t] = (t < NBLKN) ? bsum[t] : 0;
  __syncthreads();
  for (int o = 1; o < 512; o <<= 1) {
    int v = (t >= o) ? sm[t - o] : 0;
    __syncthreads();
    sm[t] += v;
    __syncthreads();
  }
  if (t < NBLKN) bbase[t] = (t == 0) ? 0 : sm[t - 1];
}

// ---------------- ksC: per-element offsets + dp fill ----------------
__global__ void __launch_bounds__(256) ksC(const int* __restrict__ hist,
                                           const int* __restrict__ bbase,
                                           int* __restrict__ off,
                                           int* __restrict__ dp) {
  __shared__ int sm[256];
  int t = threadIdx.x;
  int i = blockIdx.x * 256 + t;
  int v = (i < NNODES) ? hist[i] : 0;
  sm[t] = v;
  __syncthreads();
  for (int o = 1; o < 256; o <<= 1) {
    int u = (t >= o) ? sm[t - o] : 0;
    __syncthreads();
    sm[t] += u;
    __syncthreads();
  }
  if (i < NNODES) {
    int ex = bbase[blockIdx.x] + sm[t] - v;
    off[i] = ex;
    for (int e = ex; e < ex + v; ++e) dp[e] = i;   // CSR-order dst fill
  }
  if (i == 0) off[NNODES] = NEDGES;
}

// ---------------- kpk: pack dp groups as {base, 3x u8 deltas} ----------------
__global__ void __launch_bounds__(BLK) kpk(const int* __restrict__ dp,
                                           int2* __restrict__ dpp) {
  int g = blockIdx.x * BLK + threadIdx.x;
  if (g >= NGROUP) return;
  int4 d4 = ((const int4*)dp)[g];
  int2 o;
  o.x = d4.x;
  o.y = (d4.y - d4.x) | ((d4.z - d4.x) << 8) | ((d4.w - d4.x) << 16);
  dpp[g] = o;
}

// ---------------- kp1: pos[e] = off[dst]+rank (in-place), eperm scatter -----
__global__ void __launch_bounds__(BLK) kp1(const int* __restrict__ dst,
                                           const int* __restrict__ off,
                                           int* __restrict__ rankpos,
                                           int* __restrict__ eperm) {
  int g = blockIdx.x * BLK + threadIdx.x;
  if (g >= NGROUP) return;
  int4 d4 = ((const int4*)dst)[g];
  int4 r4 = ((int4*)rankpos)[g];
  int4 p4;
  p4.x = off[d4.x] + r4.x;
  p4.y = off[d4.y] + r4.y;
  p4.z = off[d4.z] + r4.z;
  p4.w = off[d4.w] + r4.w;
  int e = 4 * g;
  eperm[p4.x] = e; eperm[p4.y] = e + 1; eperm[p4.z] = e + 2; eperm[p4.w] = e + 3;
  ((int4*)rankpos)[g] = p4;   // rankpos now holds pos[e]
}

// ---------------- kp2: gather src/H into CSR order (H -> fp16) --------------
__global__ void __launch_bounds__(BLK) kp2(const int* __restrict__ src,
                                           const float* __restrict__ Hin,
                                           const int* __restrict__ eperm,
                                           int* __restrict__ sp,
                                           __half* __restrict__ Hp) {
  int g = blockIdx.x * BLK + threadIdx.x;
  if (g >= NGROUP) return;
  int4 e4 = ((const int4*)eperm)[g];
  int4 s4;
  s4.x = src[e4.x];
  s4.y = src[e4.y];
  s4.z = src[e4.z];
  s4.w = src[e4.w];
  __half hh[12];
  int ee[4] = {e4.x, e4.y, e4.z, e4.w};
  #pragma unroll
  for (int k = 0; k < 4; ++k) {
    size_t e3 = 3 * (size_t)ee[k];
    hh[3 * k]     = __float2half(Hin[e3]);
    hh[3 * k + 1] = __float2half(Hin[e3 + 1]);
    hh[3 * k + 2] = __float2half(Hin[e3 + 2]);
  }
  ((int4*)sp)[g] = s4;
  H4* Hv = (H4*)(Hp + 12 * (size_t)g);
  H4 a, b, c;
  #pragma unroll
  for (int i = 0; i < 4; ++i) { a.h[i] = hh[i]; b.h[i] = hh[4 + i]; c.h[i] = hh[8 + i]; }
  Hv[0] = a; Hv[1] = b; Hv[2] = c;
}

// ---------------- K1: x = e_in @ W1 + b1; STORE x (fp16x4); stats of x ------
// Exact-residency grid (GRIDR): threads stride over groups; the 2nd unit
// continues inside resident waves instead of paying a tail-generation ramp.
__global__ void __launch_bounds__(BLK) k1(
    const float* __restrict__ M, const __half* __restrict__ H,
    __half* __restrict__ xb,
    const int* __restrict__ sp, const int2* __restrict__ dpp,
    const float* __restrict__ W1, const float* __restrict__ b1,
    double* __restrict__ acc1, double* __restrict__ acc2) {
  int tid = blockIdx.x * BLK + threadIdx.x;
  if (blockIdx.x == 0)
    for (int i = threadIdx.x; i < NB * 8; i += BLK) acc2[i] = 0.0;

  float sx[4] = {0, 0, 0, 0}, sq[4] = {0, 0, 0, 0};
  for (int g = tid; g < NGROUP; g += GRIDR * BLK) {
    int4 s4 = ((const int4*)sp)[g];
    int2 dppg = dpp[g];
    int d0 = dppg.x;
    int d1 = d0 + (dppg.y & 255);
    int d2 = d0 + ((dppg.y >> 8) & 255);
    int d3 = d0 + ((dppg.y >> 16) & 255);
    const H4* Hv = (const H4*)(H + 12 * (size_t)g);
    H4 a = Hv[0], b = Hv[1], c = Hv[2];
    float hf[12];
    #pragma unroll
    for (int i = 0; i < 4; ++i) {
      hf[i] = __half2float(a.h[i]); hf[4 + i] = __half2float(b.h[i]); hf[8 + i] = __half2float(c.h[i]);
    }
    float4 mi0 = *(const float4*)(M + 4 * (size_t)d0);
    float4 mj0 = *(const float4*)(M + 4 * (size_t)s4.x);
    float4 mi1 = *(const float4*)(M + 4 * (size_t)d1);
    float4 mj1 = *(const float4*)(M + 4 * (size_t)s4.y);
    float4 mi2 = *(const float4*)(M + 4 * (size_t)d2);
    float4 mj2 = *(const float4*)(M + 4 * (size_t)s4.z);
    float4 mi3 = *(const float4*)(M + 4 * (size_t)d3);
    float4 mj3 = *(const float4*)(M + 4 * (size_t)s4.w);
    float x[4][4];
    compute_x(mi0, mj0, hf[0], hf[1], hf[2],  W1, b1, x[0]);
    compute_x(mi1, mj1, hf[3], hf[4], hf[5],  W1, b1, x[1]);
    compute_x(mi2, mj2, hf[6], hf[7], hf[8],  W1, b1, x[2]);
    compute_x(mi3, mj3, hf[9], hf[10], hf[11], W1, b1, x[3]);
    // round to fp16 (what k2 will read back); stats on the ROUNDED values
    H4* xv = (H4*)xb + 4 * (size_t)g;
    #pragma unroll
    for (int k = 0; k < 4; ++k) {
      H4 xo;
      #pragma unroll
      for (int j = 0; j < 4; ++j) {
        __half hx = __float2half(x[k][j]);
        xo.h[j] = hx;
        float xr = __half2float(hx);
        sx[j] += xr; sq[j] += xr * xr;
      }
      xv[k] = xo;
    }
  }
  float vals[8] = {sx[0], sx[1], sx[2], sx[3], sq[0], sq[1], sq[2], sq[3]};
  block_stats_atomic<8>(vals, acc1 + (size_t)(blockIdx.x & (NB - 1)) * 8);
}

// ---------------- K2: Hn per edge (IN PLACE over H) + stats of z ------------
// Exact-residency grid-stride; pure streaming body.
__global__ void __launch_bounds__(BLK) k2(
    const float* __restrict__ M, __half* __restrict__ Hn,
    const __half* __restrict__ xb, const int2* __restrict__ dpp,
    const float* __restrict__ g1, const float* __restrict__ be1,
    const float* __restrict__ W2, const float* __restrict__ b2,
    const float* __restrict__ V1, const float* __restrict__ vb1,
    const double* __restrict__ acc1, double* __restrict__ acc2,
    int isFinal,
    const float* __restrict__ OW1, const float* __restrict__ ob1,
    double* __restrict__ accF) {
  double red[8];
  bank_reduce<8>(acc1, red);
  float s1[4], t1[4];
  bn_coeff(red, 4, g1, be1, s1, t1);
  float sz[3] = {0, 0, 0}, szz[3] = {0, 0, 0}, sf[3] = {0, 0, 0}, sff[3] = {0, 0, 0};
  int tid = blockIdx.x * BLK + threadIdx.x;
  for (int g = tid; g < NGROUP; g += GRIDR * BLK) {
    int2 dppg = dpp[g];
    int dd[4];
    dd[0] = dppg.x;
    dd[1] = dd[0] + (dppg.y & 255);
    dd[2] = dd[0] + ((dppg.y >> 8) & 255);
    dd[3] = dd[0] + ((dppg.y >> 16) & 255);
    float4 mi[4];
    mi[0] = *(const float4*)(M + 4 * (size_t)dd[0]);
    mi[1] = *(const float4*)(M + 4 * (size_t)dd[1]);
    mi[2] = *(const float4*)(M + 4 * (size_t)dd[2]);
    mi[3] = *(const float4*)(M + 4 * (size_t)dd[3]);
    const H4* xv = (const H4*)xb + 4 * (size_t)g;
    __half hh[12];
    #pragma unroll
    for (int k = 0; k < 4; ++k) {
      H4 xh = xv[k];
      float y[4];
      #pragma unroll
      for (int j = 0; j < 4; ++j)
        y[j] = fmaxf(__half2float(xh.h[j]) * s1[j] + t1[j], 0.f);
      float hr[3];
      #pragma unroll
      for (int c = 0; c < 3; ++c) {
        float v = b2[c] + y[0] * W2[0 * 3 + c] + y[1] * W2[1 * 3 + c]
                        + y[2] * W2[2 * 3 + c] + y[3] * W2[3 * 3 + c];
        __half hv = __float2half(v);
        hh[3 * k + c] = hv;
        hr[c] = __half2float(hv);   // rounded value: what k1/k3 will read back
      }
      #pragma unroll
      for (int c = 0; c < 3; ++c) {
        float z = vb1[c] + mi[k].x * V1[0 * 3 + c] + mi[k].y * V1[1 * 3 + c] + mi[k].z * V1[2 * 3 + c]
                         + hr[0] * V1[3 * 3 + c] + hr[1] * V1[4 * 3 + c] + hr[2] * V1[5 * 3 + c];
        sz[c] += z; szz[c] += z * z;
      }
      if (isFinal) {
        #pragma unroll
        for (int c = 0; c < 3; ++c) {
          float f = ob1[c] + hr[0] * OW1[0 * 3 + c] + hr[1] * OW1[1 * 3 + c] + hr[2] * OW1[2 * 3 + c];
          sf[c] += f; sff[c] += f * f;
        }
      }
    }
    H4* Hw = (H4*)(Hn + 12 * (size_t)g);
    H4 oA, oB, oC;
    #pragma unroll
    for (int i = 0; i < 4; ++i) { oA.h[i] = hh[i]; oB.h[i] = hh[4 + i]; oC.h[i] = hh[8 + i]; }
    Hw[0] = oA; Hw[1] = oB; Hw[2] = oC;
  }
  size_t bank = (size_t)(blockIdx.x & (NB - 1)) * 8;
  float v6[6] = {sz[0], sz[1], sz[2], szz[0], szz[1], szz[2]};
  block_stats_atomic<6>(v6, acc2 + bank);
  if (isFinal) {
    float v6b[6] = {sf[0], sf[1], sf[2], sff[0], sff[1], sff[2]};
    block_stats_atomic<6>(v6b, accF + bank);
  }
}

// ---------------- K3: node aggregation, 4 lanes per node; M IN PLACE --------
__global__ void __launch_bounds__(BLK) k3(
    float* __restrict__ M, const __half* __restrict__ Hn,
    const int* __restrict__ off,
    const float* __restrict__ V1, const float* __restrict__ vb1,
    const float* __restrict__ vg1, const float* __restrict__ vbe1,
    const float* __restrict__ V2, const float* __restrict__ vb2,
    const double* __restrict__ acc2, double* __restrict__ acc1) {
  double red[6];
  bank_reduce<6>(acc2, red);
  float s2[3], t2[3];
  bn_coeff(red, 3, vg1, vbe1, s2, t2);
  if (blockIdx.x == 0)
    for (int i = threadIdx.x; i < NB * 8; i += BLK) acc1[i] = 0.0;

  int idx = blockIdx.x * BLK + threadIdx.x;
  int v = idx >> 2, q = idx & 3;
  if (v >= NNODES) return;
  float4 mi = *(const float4*)(M + 4 * (size_t)v);
  // hoist the mi-dependent prefix of z (same association order -> bit-identical)
  float zc[3];
  #pragma unroll
  for (int c = 0; c < 3; ++c)
    zc[c] = vb1[c] + mi.x * V1[0 * 3 + c] + mi.y * V1[1 * 3 + c] + mi.z * V1[2 * 3 + c];
  int e0 = off[v], e1 = off[v + 1];
  float a0 = 0.f, a1 = 0.f, a2v = 0.f;
  int cnt = 0;
  for (int e = e0 + q; e < e1; e += 4) {
    size_t e3 = 3 * (size_t)e;
    float h0 = __half2float(Hn[e3]), h1 = __half2float(Hn[e3 + 1]), h2 = __half2float(Hn[e3 + 2]);
    float y[3];
    #pragma unroll
    for (int c = 0; c < 3; ++c) {
      float z = zc[c] + h0 * V1[3 * 3 + c] + h1 * V1[4 * 3 + c] + h2 * V1[5 * 3 + c];
      y[c] = fmaxf(z * s2[c] + t2[c], 0.f);
    }
    a0  += y[0] * V2[0] + y[1] * V2[3] + y[2] * V2[6];
    a1  += y[0] * V2[1] + y[1] * V2[4] + y[2] * V2[7];
    a2v += y[0] * V2[2] + y[1] * V2[5] + y[2] * V2[8];
    ++cnt;
  }
  a0  += vb2[0] * (float)cnt;            // per-edge bias, hoisted
  a1  += vb2[1] * (float)cnt;
  a2v += vb2[2] * (float)cnt;
  a0  += __shfl_down(a0, 2, 4);  a0  += __shfl_down(a0, 1, 4);
  a1  += __shfl_down(a1, 2, 4);  a1  += __shfl_down(a1, 1, 4);
  a2v += __shfl_down(a2v, 2, 4); a2v += __shfl_down(a2v, 1, 4);
  if (q == 0) {
    float4 o; o.x = a0; o.y = a1; o.z = a2v; o.w = 0.f;
    *(float4*)(M + 4 * (size_t)v) = o;
  }
}

// ---------------- head: gather H via pos, streamed out writes ----------------
__global__ void __launch_bounds__(BLK) f2(
    const __half* __restrict__ H, const int* __restrict__ pos,
    const float* __restrict__ OW1, const float* __restrict__ ob1,
    const float* __restrict__ og, const float* __restrict__ obe,
    const float* __restrict__ OW2, const float* __restrict__ ob2,
    const double* __restrict__ accF, float* __restrict__ out) {
  double red[6];
  bank_reduce<6>(accF, red);
  float sF[3], tF[3];
  bn_coeff(red, 3, og, obe, sF, tF);
  int g = blockIdx.x * BLK + threadIdx.x;
  if (g >= NGROUP) return;
  int4 p4 = ((const int4*)pos)[g];
  int p[4] = {p4.x, p4.y, p4.z, p4.w};
  float2 o[4];
  #pragma unroll
  for (int k = 0; k < 4; ++k) {
    size_t p3 = 3 * (size_t)p[k];
    float h0 = __half2float(H[p3]), h1 = __half2float(H[p3 + 1]), h2 = __half2float(H[p3 + 2]);
    float y[3];
    #pragma unroll
    for (int c = 0; c < 3; ++c) {
      float f = ob1[c] + h0 * OW1[0 * 3 + c] + h1 * OW1[1 * 3 + c] + h2 * OW1[2 * 3 + c];
      y[c] = fmaxf(f * sF[c] + tF[c], 0.f);
    }
    float l0 = ob2[0] + y[0] * OW2[0] + y[1] * OW2[2] + y[2] * OW2[4];
    float l1 = ob2[1] + y[0] * OW2[1] + y[1] * OW2[3] + y[2] * OW2[5];
    float mx = fmaxf(l0, l1);
    float e0 = __expf(l0 - mx), e1 = __expf(l1 - mx);
    float inv = 1.f / (e0 + e1);
    o[k].x = e0 * inv; o[k].y = e1 * inv;
  }
  float4 oA, oB;
  oA.x = o[0].x; oA.y = o[0].y; oA.z = o[1].x; oA.w = o[1].y;
  oB.x = o[2].x; oB.y = o[2].y; oB.z = o[3].x; oB.w = o[3].y;
  ((float4*)out)[2 * (size_t)g] = oA;
  ((float4*)out)[2 * (size_t)g + 1] = oB;
}

extern "C" void kernel_launch(void* const* d_in, const int* in_sizes, int n_in,
                              void* d_out, int out_size, void* d_ws, size_t ws_size,
                              hipStream_t stream) {
  const float* M_in   = (const float*)d_in[0];
  const float* H_in   = (const float*)d_in[1];
  const int*   ei     = (const int*)d_in[2];
  const float* we_w1  = (const float*)d_in[3];
  const float* we_b1  = (const float*)d_in[4];
  const float* we_g1  = (const float*)d_in[5];
  const float* we_be1 = (const float*)d_in[6];
  const float* we_w2  = (const float*)d_in[7];
  const float* we_b2  = (const float*)d_in[8];
  const float* wv_w1  = (const float*)d_in[9];
  const float* wv_b1  = (const float*)d_in[10];
  const float* wv_g1  = (const float*)d_in[11];
  const float* wv_be1 = (const float*)d_in[12];
  const float* wv_w2  = (const float*)d_in[13];
  const float* wv_b2  = (const float*)d_in[14];
  const float* out_w1 = (const float*)d_in[15];
  const float* out_b1 = (const float*)d_in[16];
  const float* out_g  = (const float*)d_in[17];
  const float* out_be = (const float*)d_in[18];
  const float* out_w2 = (const float*)d_in[19];
  const float* out_b2 = (const float*)d_in[20];
  const int* src = ei;
  const int* dst = ei + NEDGES;

  float* ws = (float*)d_ws;
  float* M    = ws;                          // N*4 floats (in-place across layers)
  __half* Hp  = (__half*)(ws + 400000);      // E*3 halfs (single buffer, in-place)
  __half* xb  = (__half*)(ws + 2800000);     // E*4 halfs staged x (16B-aligned)
  int* ib      = (int*)(ws + 6000000);       // 16B-aligned int region
  int* sp      = ib;                         // E
  int* dp      = ib + 1600000;               // E (CSR dst, setup only)
  int* rankpos = ib + 3200000;               // E (rank, then pos)
  int2* dpp    = (int2*)(ib + 4800000);      // E/4 int2 = E/2 ints
  int* hist    = ib + 5600000;               // N
  int* off     = ib + 5700000;               // N+1
  int* bsum    = ib + 5800001;               // 400
  int* bbase   = ib + 5800401;               // 400
  double* accs = (double*)(ws + 6000000 + 5800802);  // even float idx -> 8B-aligned
  double* acc1 = accs;
  double* acc2 = accs + NB * 8;
  double* accF = accs + 2 * NB * 8;
  int* eperm   = dp;   // alias: dp dead after kpk, eperm born in kp1

  // --- build CSR permutation (ws is re-poisoned between replays) ---
  kz<<<GRIDE, BLK, 0, stream>>>(M_in, M, hist, accs);
  khr<<<GRIDL, BLK, 0, stream>>>(dst, hist, rankpos);
  ksA<<<NBLKN, 256, 0, stream>>>(hist, bsum);
  ksB<<<1, 512, 0, stream>>>(bsum, bbase);
  ksC<<<NBLKN, 256, 0, stream>>>(hist, bbase, off, dp);
  kpk<<<GRIDL, BLK, 0, stream>>>(dp, dpp);
  kp1<<<GRIDL, BLK, 0, stream>>>(dst, off, rankpos, eperm);
  kp2<<<GRIDL, BLK, 0, stream>>>(src, H_in, eperm, sp, Hp);

  for (int l = 0; l < NLAYERS; ++l) {
    k1<<<GRIDR, BLK, 0, stream>>>(M, Hp, xb, sp, dpp, we_w1, we_b1, acc1, acc2);
    k2<<<GRIDR, BLK, 0, stream>>>(M, Hp, xb, dpp, we_g1, we_be1,
                                  we_w2, we_b2, wv_w1, wv_b1, acc1, acc2,
                                  (l == NLAYERS - 1) ? 1 : 0, out_w1, out_b1, accF);
    if (l < NLAYERS - 1)
      k3<<<GRIDN4, BLK, 0, stream>>>(
          M, Hp, off, wv_w1, wv_b1, wv_g1, wv_be1, wv_w2, wv_b2, acc2, acc1);
  }
  f2<<<GRIDL, BLK, 0, stream>>>(Hp, rankpos, out_w1, out_b1, out_g, out_be,
                                out_w2, out_b2, accF, (float*)d_out);
}